// Round 7
// baseline (221.404 us; speedup 1.0000x reference)
//
#include <hip/hip_runtime.h>

#define L 4096
#define CCH 256
#define NB 4
#define KP 40   // padded LDS row length (32 k + 8 pad) in bf16 elems; 80 B rows

typedef __attribute__((ext_vector_type(8))) short short8;
typedef __attribute__((ext_vector_type(4))) float f32x4;
typedef unsigned short ushort_t;

__device__ __forceinline__ unsigned short f2bf(float f) {
    unsigned u = __builtin_bit_cast(unsigned, f);
    u += 0x7FFF + ((u >> 16) & 1);
    return (unsigned short)(u >> 16);
}
__device__ __forceinline__ float bflo(unsigned w) {
    return __builtin_bit_cast(float, w << 16);
}
__device__ __forceinline__ float bfhi(unsigned w) {
    return __builtin_bit_cast(float, w & 0xFFFF0000u);
}

// ---------------------------------------------------------------------------
// Dual conv1x1 via bf16 MFMA; bf16 outputs + fused BN partial stats
// (per-channel sum/sumsq atomics from f32 accumulators).
// ---------------------------------------------------------------------------
__global__ __launch_bounds__(256, 2) void dual_gemm_k(
    const float* __restrict__ x,
    const float* __restrict__ w1, const float* __restrict__ b1,
    const float* __restrict__ w2, const float* __restrict__ b2,
    ushort_t* __restrict__ y1, ushort_t* __restrict__ y2,
    float* __restrict__ gs1, float* __restrict__ gss1,
    float* __restrict__ gs2, float* __restrict__ gss2)
{
    __shared__ short sA1[128 * KP];
    __shared__ short sA2[128 * KP];
    __shared__ short sB [64 * KP];

    const int tid = threadIdx.x;
    const int l0 = blockIdx.x * 64;
    const int o0 = blockIdx.y * 128;
    const int b  = blockIdx.z;

    const int wv = tid >> 6;
    const int lane = tid & 63;
    const int m = lane & 15;
    const int quad = lane >> 4;

    const float* xb = x + (size_t)b * CCH * L;

    const int sl = tid & 63, soct = tid >> 6;
    const int sr = tid & 127, sh = tid >> 7;

    f32x4 acc1[2][4], acc2[2][4];
    #pragma unroll
    for (int io = 0; io < 2; ++io)
        #pragma unroll
        for (int jl = 0; jl < 4; ++jl) {
            acc1[io][jl] = (f32x4){0.f,0.f,0.f,0.f};
            acc2[io][jl] = (f32x4){0.f,0.f,0.f,0.f};
        }

    for (int s = 0; s < 8; ++s) {
        const int k0 = s * 32;
        __syncthreads();
        {
            const float* xs = xb + (size_t)(k0 + soct * 8) * L + l0 + sl;
            short8 v;
            #pragma unroll
            for (int j = 0; j < 8; ++j) v[j] = (short)f2bf(xs[(size_t)j * L]);
            *(short8*)&sB[sl * KP + soct * 8] = v;
        }
        {
            const float4* wp = (const float4*)&w1[(size_t)(o0 + sr) * CCH + k0 + sh * 16];
            float4 c0 = wp[0], c1 = wp[1], c2 = wp[2], c3 = wp[3];
            short8 p0 = {(short)f2bf(c0.x),(short)f2bf(c0.y),(short)f2bf(c0.z),(short)f2bf(c0.w),
                         (short)f2bf(c1.x),(short)f2bf(c1.y),(short)f2bf(c1.z),(short)f2bf(c1.w)};
            short8 p1 = {(short)f2bf(c2.x),(short)f2bf(c2.y),(short)f2bf(c2.z),(short)f2bf(c2.w),
                         (short)f2bf(c3.x),(short)f2bf(c3.y),(short)f2bf(c3.z),(short)f2bf(c3.w)};
            *(short8*)&sA1[sr * KP + sh * 16]     = p0;
            *(short8*)&sA1[sr * KP + sh * 16 + 8] = p1;
            const float4* wq = (const float4*)&w2[(size_t)(o0 + sr) * CCH + k0 + sh * 16];
            float4 d0 = wq[0], d1 = wq[1], d2 = wq[2], d3 = wq[3];
            short8 q0 = {(short)f2bf(d0.x),(short)f2bf(d0.y),(short)f2bf(d0.z),(short)f2bf(d0.w),
                         (short)f2bf(d1.x),(short)f2bf(d1.y),(short)f2bf(d1.z),(short)f2bf(d1.w)};
            short8 q1 = {(short)f2bf(d2.x),(short)f2bf(d2.y),(short)f2bf(d2.z),(short)f2bf(d2.w),
                         (short)f2bf(d3.x),(short)f2bf(d3.y),(short)f2bf(d3.z),(short)f2bf(d3.w)};
            *(short8*)&sA2[sr * KP + sh * 16]     = q0;
            *(short8*)&sA2[sr * KP + sh * 16 + 8] = q1;
        }
        __syncthreads();
        short8 a1[2], a2[2], bf[4];
        #pragma unroll
        for (int io = 0; io < 2; ++io) {
            a1[io] = *(const short8*)&sA1[(wv * 32 + io * 16 + m) * KP + quad * 8];
            a2[io] = *(const short8*)&sA2[(wv * 32 + io * 16 + m) * KP + quad * 8];
        }
        #pragma unroll
        for (int jl = 0; jl < 4; ++jl)
            bf[jl] = *(const short8*)&sB[(jl * 16 + m) * KP + quad * 8];
        #pragma unroll
        for (int io = 0; io < 2; ++io)
            #pragma unroll
            for (int jl = 0; jl < 4; ++jl) {
                acc1[io][jl] = __builtin_amdgcn_mfma_f32_16x16x32_bf16(a1[io], bf[jl], acc1[io][jl], 0, 0, 0);
                acc2[io][jl] = __builtin_amdgcn_mfma_f32_16x16x32_bf16(a2[io], bf[jl], acc2[io][jl], 0, 0, 0);
            }
    }

    // epilogue: bf16 store + per-row stat partials (cross-16-lane reduce + atomics)
    #pragma unroll
    for (int io = 0; io < 2; ++io)
        #pragma unroll
        for (int reg = 0; reg < 4; ++reg) {
            const int o = o0 + wv * 32 + io * 16 + quad * 4 + reg;
            const float bb1 = b1[o], bb2 = b2[o];
            const size_t ro = ((size_t)b * CCH + o) * L + l0 + m;
            float s1 = 0.f, q1 = 0.f, s2 = 0.f, q2 = 0.f;
            #pragma unroll
            for (int jl = 0; jl < 4; ++jl) {
                float v1 = acc1[io][jl][reg] + bb1;
                float v2 = acc2[io][jl][reg] + bb2;
                y1[ro + jl * 16] = f2bf(v1);
                y2[ro + jl * 16] = f2bf(v2);
                s1 += v1; q1 += v1 * v1;
                s2 += v2; q2 += v2 * v2;
            }
            #pragma unroll
            for (int d = 1; d < 16; d <<= 1) {
                s1 += __shfl_xor(s1, d); q1 += __shfl_xor(q1, d);
                s2 += __shfl_xor(s2, d); q2 += __shfl_xor(q2, d);
            }
            if (m == 0) {
                atomicAdd(&gs1[o], s1); atomicAdd(&gss1[o], q1);
                atomicAdd(&gs2[o], s2); atomicAdd(&gss2[o], q2);
            }
        }
}

// ---------------------------------------------------------------------------
// Single conv1x1 via bf16 MFMA: bf16 input (pre), bf16 output + fused stats
// ---------------------------------------------------------------------------
__global__ __launch_bounds__(256, 2) void single_gemm_k(
    const ushort_t* __restrict__ x,
    const float* __restrict__ w, const float* __restrict__ bb,
    ushort_t* __restrict__ y,
    float* __restrict__ gsf, float* __restrict__ gssf)
{
    __shared__ short sA[128 * KP];
    __shared__ short sB[64 * KP];

    const int tid = threadIdx.x;
    const int l0 = blockIdx.x * 64;
    const int o0 = blockIdx.y * 128;
    const int b  = blockIdx.z;

    const int wv = tid >> 6;
    const int lane = tid & 63;
    const int m = lane & 15;
    const int quad = lane >> 4;

    const ushort_t* xb = x + (size_t)b * CCH * L;

    const int sl = tid & 63, soct = tid >> 6;
    const int sr = tid & 127, sh = tid >> 7;

    f32x4 acc[2][4];
    #pragma unroll
    for (int io = 0; io < 2; ++io)
        #pragma unroll
        for (int jl = 0; jl < 4; ++jl)
            acc[io][jl] = (f32x4){0.f,0.f,0.f,0.f};

    for (int s = 0; s < 8; ++s) {
        const int k0 = s * 32;
        __syncthreads();
        {
            const ushort_t* xs = xb + (size_t)(k0 + soct * 8) * L + l0 + sl;
            short8 v;
            #pragma unroll
            for (int j = 0; j < 8; ++j) v[j] = (short)xs[(size_t)j * L];
            *(short8*)&sB[sl * KP + soct * 8] = v;
        }
        {
            const float4* wp = (const float4*)&w[(size_t)(o0 + sr) * CCH + k0 + sh * 16];
            float4 c0 = wp[0], c1 = wp[1], c2 = wp[2], c3 = wp[3];
            short8 p0 = {(short)f2bf(c0.x),(short)f2bf(c0.y),(short)f2bf(c0.z),(short)f2bf(c0.w),
                         (short)f2bf(c1.x),(short)f2bf(c1.y),(short)f2bf(c1.z),(short)f2bf(c1.w)};
            short8 p1 = {(short)f2bf(c2.x),(short)f2bf(c2.y),(short)f2bf(c2.z),(short)f2bf(c2.w),
                         (short)f2bf(c3.x),(short)f2bf(c3.y),(short)f2bf(c3.z),(short)f2bf(c3.w)};
            *(short8*)&sA[sr * KP + sh * 16]     = p0;
            *(short8*)&sA[sr * KP + sh * 16 + 8] = p1;
        }
        __syncthreads();
        short8 a[2], bf[4];
        #pragma unroll
        for (int io = 0; io < 2; ++io)
            a[io] = *(const short8*)&sA[(wv * 32 + io * 16 + m) * KP + quad * 8];
        #pragma unroll
        for (int jl = 0; jl < 4; ++jl)
            bf[jl] = *(const short8*)&sB[(jl * 16 + m) * KP + quad * 8];
        #pragma unroll
        for (int io = 0; io < 2; ++io)
            #pragma unroll
            for (int jl = 0; jl < 4; ++jl)
                acc[io][jl] = __builtin_amdgcn_mfma_f32_16x16x32_bf16(a[io], bf[jl], acc[io][jl], 0, 0, 0);
    }

    #pragma unroll
    for (int io = 0; io < 2; ++io)
        #pragma unroll
        for (int reg = 0; reg < 4; ++reg) {
            const int o = o0 + wv * 32 + io * 16 + quad * 4 + reg;
            const float b0 = bb[o];
            const size_t ro = ((size_t)b * CCH + o) * L + l0 + m;
            float s = 0.f, q = 0.f;
            #pragma unroll
            for (int jl = 0; jl < 4; ++jl) {
                float v = acc[io][jl][reg] + b0;
                y[ro + jl * 16] = f2bf(v);
                s += v; q += v * v;
            }
            #pragma unroll
            for (int d = 1; d < 16; d <<= 1) {
                s += __shfl_xor(s, d); q += __shfl_xor(q, d);
            }
            if (m == 0) {
                atomicAdd(&gsf[o], s); atomicAdd(&gssf[o], q);
            }
        }
}

// ---------------------------------------------------------------------------
// Attention, two-phase, no atomics; bf16 y1/y2 inputs, inline BN finalize,
// bf16 pre output. LDS 64 KB -> 2 blocks/CU.
// ---------------------------------------------------------------------------
__global__ __launch_bounds__(512, 4) void attention_k(
    const float* __restrict__ x,
    const ushort_t* __restrict__ y1,
    const ushort_t* __restrict__ y2,
    const float* __restrict__ g1, const float* __restrict__ be1,
    const float* __restrict__ g2, const float* __restrict__ be2,
    const float* __restrict__ gs1, const float* __restrict__ gss1,
    const float* __restrict__ gs2, const float* __restrict__ gss2,
    ushort_t* __restrict__ pre)
{
    __shared__ unsigned sKQ[L];   // 16 KB: bf16 k (lo), q (hi)
    __shared__ float    sXv[L];   // 16 KB
    __shared__ uint2    sCI[L];   // 32 KB: {packed (kc,qc), bits(-ln S)}

    const int bc = blockIdx.x;
    const int tid = threadIdx.x;
    const int ch = bc & 255;
    const size_t off = (size_t)bc * L;

    const float invN = 1.f / (NB * (float)L);
    float mu1 = gs1[ch] * invN;
    float va1 = gss1[ch] * invN - mu1 * mu1;
    float r1 = rsqrtf(va1 + 1e-5f);
    const float sc1 = g1[ch] * r1, sh1 = be1[ch] - mu1 * g1[ch] * r1;
    float mu2 = gs2[ch] * invN;
    float va2 = gss2[ch] * invN - mu2 * mu2;
    float r2 = rsqrtf(va2 + 1e-5f);
    const float sc2 = g2[ch] * r2, sh2 = be2[ch] - mu2 * g2[ch] * r2;

    const float4* x4 = (const float4*)(x + off);

    {
        uint4 ak = ((const uint4*)(y1 + off))[tid];
        uint4 aq = ((const uint4*)(y2 + off))[tid];
        unsigned wks[4] = {ak.x, ak.y, ak.z, ak.w};
        unsigned wqs[4] = {aq.x, aq.y, aq.z, aq.w};
        #pragma unroll
        for (int u = 0; u < 4; ++u) {
            float klo = fmaxf(fmaf(bflo(wks[u]), sc1, sh1), 0.f);
            float khi = fmaxf(fmaf(bfhi(wks[u]), sc1, sh1), 0.f);
            float qlo = fmaxf(fmaf(bflo(wqs[u]), sc2, sh2), 0.f);
            float qhi = fmaxf(fmaf(bfhi(wqs[u]), sc2, sh2), 0.f);
            sKQ[8 * tid + 2 * u]     = (unsigned)f2bf(klo) | ((unsigned)f2bf(qlo) << 16);
            sKQ[8 * tid + 2 * u + 1] = (unsigned)f2bf(khi) | ((unsigned)f2bf(qhi) << 16);
        }
        ((float4*)sXv)[2 * tid]     = x4[2 * tid];
        ((float4*)sXv)[2 * tid + 1] = x4[2 * tid + 1];
    }
    __syncthreads();

    // ---- Phase 1: per-window center + -ln(denominator) ----------------
    #pragma unroll
    for (int r = 0; r < 8; ++r) {
        const int lp = r * 512 + tid;
        const int base = 9 * lp;
        float kv[9], qv[9];
        unsigned cw = 0;
        #pragma unroll
        for (int j = 0; j < 9; ++j) {
            int f = base + j;
            int t = f >> 12;
            int l = f & 4095;
            int di = (t * 86) >> 8;     // t/3
            int dj = t - di * 3;
            int ii = (l >> 6) + di - 1;
            int jj = (l & 63) + dj - 1;
            bool ok = ((unsigned)ii < 64u) && ((unsigned)jj < 64u);
            int src = ((ii << 6) + jj) & 4095;
            unsigned w = sKQ[src];
            w = ok ? w : 0u;
            if (j == 4) cw = w;
            kv[j] = bflo(w);
            qv[j] = bfhi(w);
        }
        const float kc = kv[4], qc = qv[4];
        float s01 = __expf(kv[0] * qc + kc * qv[0]) + __expf(kv[1] * qc + kc * qv[1]);
        float s23 = __expf(kv[2] * qc + kc * qv[2]) + __expf(kv[3] * qc + kc * qv[3]);
        float s45 = __expf(kv[4] * qc + kc * qv[4]) + __expf(kv[5] * qc + kc * qv[5]);
        float s67 = __expf(kv[6] * qc + kc * qv[6]) + __expf(kv[7] * qc + kc * qv[7]);
        float s = ((s01 + s23) + (s45 + s67)) + __expf(kv[8] * qc + kc * qv[8]);
        uint2 ci;
        ci.x = cw;
        ci.y = __builtin_bit_cast(unsigned, -__logf(s));
        sCI[lp] = ci;
    }
    __syncthreads();

    // ---- Phase 2: per-output accumulate -------------------------------
    #pragma unroll
    for (int r = 0; r < 8; ++r) {
        const int l = r * 512 + tid;
        const int li = l >> 6, lj = l & 63;
        float acc = 0.f;
        #pragma unroll
        for (int t = 0; t < 9; ++t) {
            const int f = (t << 12) + l;
            const unsigned lp = (unsigned)f / 9u;           // magic-mul
            uint2 ci = sCI[lp];
            const float kc = bflo(ci.x), qc = bfhi(ci.x);
            const float cn = __builtin_bit_cast(float, ci.y);
            const int di = t / 3, dj = t % 3;               // constants
            int ii = li + di - 1;
            int jj = lj + dj - 1;
            bool ok = ((unsigned)ii < 64u) && ((unsigned)jj < 64u);
            int src = ((ii << 6) + jj) & 4095;
            unsigned w = sKQ[src];
            float xj = sXv[src];
            w  = ok ? w : 0u;
            xj = ok ? xj : 0.f;
            const float kj = bflo(w), qj = bfhi(w);
            float e = __expf(fmaf(kj, qc, fmaf(kc, qj, cn)));
            acc = fmaf(e, xj, acc);
        }
        pre[off + l] = f2bf(acc);
    }
}

// ---------------------------------------------------------------------------
// Final BN apply + ReLU: bf16 in, f32 out, inline stats finalize
// ---------------------------------------------------------------------------
__global__ __launch_bounds__(256) void bn_apply_k(
    const ushort_t* __restrict__ yf,
    const float* __restrict__ gf, const float* __restrict__ bef,
    const float* __restrict__ gsf, const float* __restrict__ gssf,
    float* __restrict__ out)
{
    const int i = blockIdx.x * 256 + threadIdx.x;   // uint4 index (8 elems)
    const int ch = (i >> 9) & 255;
    const float invN = 1.f / (NB * (float)L);
    float mu = gsf[ch] * invN;
    float va = gssf[ch] * invN - mu * mu;
    float r = rsqrtf(va + 1e-5f);
    const float sc = gf[ch] * r, sh = bef[ch] - mu * gf[ch] * r;

    uint4 v = ((const uint4*)yf)[i];
    unsigned w[4] = {v.x, v.y, v.z, v.w};
    float4 o0, o1;
    o0.x = fmaxf(fmaf(bflo(w[0]), sc, sh), 0.f);
    o0.y = fmaxf(fmaf(bfhi(w[0]), sc, sh), 0.f);
    o0.z = fmaxf(fmaf(bflo(w[1]), sc, sh), 0.f);
    o0.w = fmaxf(fmaf(bfhi(w[1]), sc, sh), 0.f);
    o1.x = fmaxf(fmaf(bflo(w[2]), sc, sh), 0.f);
    o1.y = fmaxf(fmaf(bfhi(w[2]), sc, sh), 0.f);
    o1.z = fmaxf(fmaf(bflo(w[3]), sc, sh), 0.f);
    o1.w = fmaxf(fmaf(bfhi(w[3]), sc, sh), 0.f);
    ((float4*)out)[2 * i]     = o0;
    ((float4*)out)[2 * i + 1] = o1;
}

// ---------------------------------------------------------------------------
extern "C" void kernel_launch(void* const* d_in, const int* in_sizes, int n_in,
                              void* d_out, int out_size, void* d_ws, size_t ws_size,
                              hipStream_t stream) {
    const float* x   = (const float*)d_in[0];
    const float* w1  = (const float*)d_in[1];
    const float* b1  = (const float*)d_in[2];
    const float* g1  = (const float*)d_in[3];
    const float* be1 = (const float*)d_in[4];
    const float* w2  = (const float*)d_in[5];
    const float* b2  = (const float*)d_in[6];
    const float* g2  = (const float*)d_in[7];
    const float* be2 = (const float*)d_in[8];
    const float* wf  = (const float*)d_in[9];
    const float* bf  = (const float*)d_in[10];
    const float* gf  = (const float*)d_in[11];
    const float* bef = (const float*)d_in[12];
    float* out = (float*)d_out;

    const size_t NEL = (size_t)NB * CCH * L;       // 4194304
    ushort_t* y1b = (ushort_t*)d_ws;               // conv1 out (bf16); later yf
    ushort_t* y2b = y1b + NEL;                     // conv2 out (bf16); later pre
    float* st = (float*)(y2b + NEL);               // stats accum: 6 x 256
    float* gs1 = st,        *gss1 = st + 256;
    float* gs2 = st + 512,  *gss2 = st + 768;
    float* gsf = st + 1024, *gssf = st + 1280;

    hipMemsetAsync(st, 0, 1536 * sizeof(float), stream);

    dim3 gg(64, 2, 4);
    dual_gemm_k<<<gg, 256, 0, stream>>>(x, w1, b1, w2, b2, y1b, y2b,
                                        gs1, gss1, gs2, gss2);
    attention_k<<<NB * CCH, 512, 0, stream>>>(x, y1b, y2b,
                                              g1, be1, g2, be2,
                                              gs1, gss1, gs2, gss2,
                                              /*pre=*/y2b);
    single_gemm_k<<<gg, 256, 0, stream>>>(/*pre=*/y2b, wf, bf, /*yf=*/y1b,
                                          gsf, gssf);
    bn_apply_k<<<(int)(NEL / 2048), 256, 0, stream>>>(y1b, gf, bef, gsf, gssf, out);
}

// Round 8
// 180.886 us; speedup vs baseline: 1.2240x; 1.2240x over previous
//
#include <hip/hip_runtime.h>

#define L 4096
#define CCH 256
#define NB 4
#define KP 40   // padded LDS row length (32 k + 8 pad) in bf16 elems; 80 B rows

typedef __attribute__((ext_vector_type(8))) short short8;
typedef __attribute__((ext_vector_type(4))) float f32x4;
typedef unsigned short ushort_t;

__device__ __forceinline__ unsigned short f2bf(float f) {
    unsigned u = __builtin_bit_cast(unsigned, f);
    u += 0x7FFF + ((u >> 16) & 1);
    return (unsigned short)(u >> 16);
}
__device__ __forceinline__ float bflo(unsigned w) {
    return __builtin_bit_cast(float, w << 16);
}
__device__ __forceinline__ float bfhi(unsigned w) {
    return __builtin_bit_cast(float, w & 0xFFFF0000u);
}

// ---------------------------------------------------------------------------
// Dual conv1x1 via bf16 MFMA; bf16 outputs, plain epilogue (no fused stats).
// ---------------------------------------------------------------------------
__global__ __launch_bounds__(256, 2) void dual_gemm_k(
    const float* __restrict__ x,
    const float* __restrict__ w1, const float* __restrict__ b1,
    const float* __restrict__ w2, const float* __restrict__ b2,
    ushort_t* __restrict__ y1, ushort_t* __restrict__ y2)
{
    __shared__ short sA1[128 * KP];
    __shared__ short sA2[128 * KP];
    __shared__ short sB [64 * KP];

    const int tid = threadIdx.x;
    const int l0 = blockIdx.x * 64;
    const int o0 = blockIdx.y * 128;
    const int b  = blockIdx.z;

    const int wv = tid >> 6;
    const int lane = tid & 63;
    const int m = lane & 15;
    const int quad = lane >> 4;

    const float* xb = x + (size_t)b * CCH * L;

    const int sl = tid & 63, soct = tid >> 6;
    const int sr = tid & 127, sh = tid >> 7;

    f32x4 acc1[2][4], acc2[2][4];
    #pragma unroll
    for (int io = 0; io < 2; ++io)
        #pragma unroll
        for (int jl = 0; jl < 4; ++jl) {
            acc1[io][jl] = (f32x4){0.f,0.f,0.f,0.f};
            acc2[io][jl] = (f32x4){0.f,0.f,0.f,0.f};
        }

    for (int s = 0; s < 8; ++s) {
        const int k0 = s * 32;
        __syncthreads();
        {
            const float* xs = xb + (size_t)(k0 + soct * 8) * L + l0 + sl;
            short8 v;
            #pragma unroll
            for (int j = 0; j < 8; ++j) v[j] = (short)f2bf(xs[(size_t)j * L]);
            *(short8*)&sB[sl * KP + soct * 8] = v;
        }
        {
            const float4* wp = (const float4*)&w1[(size_t)(o0 + sr) * CCH + k0 + sh * 16];
            float4 c0 = wp[0], c1 = wp[1], c2 = wp[2], c3 = wp[3];
            short8 p0 = {(short)f2bf(c0.x),(short)f2bf(c0.y),(short)f2bf(c0.z),(short)f2bf(c0.w),
                         (short)f2bf(c1.x),(short)f2bf(c1.y),(short)f2bf(c1.z),(short)f2bf(c1.w)};
            short8 p1 = {(short)f2bf(c2.x),(short)f2bf(c2.y),(short)f2bf(c2.z),(short)f2bf(c2.w),
                         (short)f2bf(c3.x),(short)f2bf(c3.y),(short)f2bf(c3.z),(short)f2bf(c3.w)};
            *(short8*)&sA1[sr * KP + sh * 16]     = p0;
            *(short8*)&sA1[sr * KP + sh * 16 + 8] = p1;
            const float4* wq = (const float4*)&w2[(size_t)(o0 + sr) * CCH + k0 + sh * 16];
            float4 d0 = wq[0], d1 = wq[1], d2 = wq[2], d3 = wq[3];
            short8 q0 = {(short)f2bf(d0.x),(short)f2bf(d0.y),(short)f2bf(d0.z),(short)f2bf(d0.w),
                         (short)f2bf(d1.x),(short)f2bf(d1.y),(short)f2bf(d1.z),(short)f2bf(d1.w)};
            short8 q1 = {(short)f2bf(d2.x),(short)f2bf(d2.y),(short)f2bf(d2.z),(short)f2bf(d2.w),
                         (short)f2bf(d3.x),(short)f2bf(d3.y),(short)f2bf(d3.z),(short)f2bf(d3.w)};
            *(short8*)&sA2[sr * KP + sh * 16]     = q0;
            *(short8*)&sA2[sr * KP + sh * 16 + 8] = q1;
        }
        __syncthreads();
        short8 a1[2], a2[2], bf[4];
        #pragma unroll
        for (int io = 0; io < 2; ++io) {
            a1[io] = *(const short8*)&sA1[(wv * 32 + io * 16 + m) * KP + quad * 8];
            a2[io] = *(const short8*)&sA2[(wv * 32 + io * 16 + m) * KP + quad * 8];
        }
        #pragma unroll
        for (int jl = 0; jl < 4; ++jl)
            bf[jl] = *(const short8*)&sB[(jl * 16 + m) * KP + quad * 8];
        #pragma unroll
        for (int io = 0; io < 2; ++io)
            #pragma unroll
            for (int jl = 0; jl < 4; ++jl) {
                acc1[io][jl] = __builtin_amdgcn_mfma_f32_16x16x32_bf16(a1[io], bf[jl], acc1[io][jl], 0, 0, 0);
                acc2[io][jl] = __builtin_amdgcn_mfma_f32_16x16x32_bf16(a2[io], bf[jl], acc2[io][jl], 0, 0, 0);
            }
    }

    #pragma unroll
    for (int io = 0; io < 2; ++io)
        #pragma unroll
        for (int reg = 0; reg < 4; ++reg) {
            const int o = o0 + wv * 32 + io * 16 + quad * 4 + reg;
            const float bb1 = b1[o], bb2 = b2[o];
            const size_t ro = ((size_t)b * CCH + o) * L + l0 + m;
            #pragma unroll
            for (int jl = 0; jl < 4; ++jl) {
                y1[ro + jl * 16] = f2bf(acc1[io][jl][reg] + bb1);
                y2[ro + jl * 16] = f2bf(acc2[io][jl][reg] + bb2);
            }
        }
}

// ---------------------------------------------------------------------------
// Single conv1x1 via bf16 MFMA: bf16 input (pre), bf16 output, plain epilogue
// ---------------------------------------------------------------------------
__global__ __launch_bounds__(256, 2) void single_gemm_k(
    const ushort_t* __restrict__ x,
    const float* __restrict__ w, const float* __restrict__ bb,
    ushort_t* __restrict__ y)
{
    __shared__ short sA[128 * KP];
    __shared__ short sB[64 * KP];

    const int tid = threadIdx.x;
    const int l0 = blockIdx.x * 64;
    const int o0 = blockIdx.y * 128;
    const int b  = blockIdx.z;

    const int wv = tid >> 6;
    const int lane = tid & 63;
    const int m = lane & 15;
    const int quad = lane >> 4;

    const ushort_t* xb = x + (size_t)b * CCH * L;

    const int sl = tid & 63, soct = tid >> 6;
    const int sr = tid & 127, sh = tid >> 7;

    f32x4 acc[2][4];
    #pragma unroll
    for (int io = 0; io < 2; ++io)
        #pragma unroll
        for (int jl = 0; jl < 4; ++jl)
            acc[io][jl] = (f32x4){0.f,0.f,0.f,0.f};

    for (int s = 0; s < 8; ++s) {
        const int k0 = s * 32;
        __syncthreads();
        {
            const ushort_t* xs = xb + (size_t)(k0 + soct * 8) * L + l0 + sl;
            short8 v;
            #pragma unroll
            for (int j = 0; j < 8; ++j) v[j] = (short)xs[(size_t)j * L];
            *(short8*)&sB[sl * KP + soct * 8] = v;
        }
        {
            const float4* wp = (const float4*)&w[(size_t)(o0 + sr) * CCH + k0 + sh * 16];
            float4 c0 = wp[0], c1 = wp[1], c2 = wp[2], c3 = wp[3];
            short8 p0 = {(short)f2bf(c0.x),(short)f2bf(c0.y),(short)f2bf(c0.z),(short)f2bf(c0.w),
                         (short)f2bf(c1.x),(short)f2bf(c1.y),(short)f2bf(c1.z),(short)f2bf(c1.w)};
            short8 p1 = {(short)f2bf(c2.x),(short)f2bf(c2.y),(short)f2bf(c2.z),(short)f2bf(c2.w),
                         (short)f2bf(c3.x),(short)f2bf(c3.y),(short)f2bf(c3.z),(short)f2bf(c3.w)};
            *(short8*)&sA[sr * KP + sh * 16]     = p0;
            *(short8*)&sA[sr * KP + sh * 16 + 8] = p1;
        }
        __syncthreads();
        short8 a[2], bf[4];
        #pragma unroll
        for (int io = 0; io < 2; ++io)
            a[io] = *(const short8*)&sA[(wv * 32 + io * 16 + m) * KP + quad * 8];
        #pragma unroll
        for (int jl = 0; jl < 4; ++jl)
            bf[jl] = *(const short8*)&sB[(jl * 16 + m) * KP + quad * 8];
        #pragma unroll
        for (int io = 0; io < 2; ++io)
            #pragma unroll
            for (int jl = 0; jl < 4; ++jl)
                acc[io][jl] = __builtin_amdgcn_mfma_f32_16x16x32_bf16(a[io], bf[jl], acc[io][jl], 0, 0, 0);
    }

    #pragma unroll
    for (int io = 0; io < 2; ++io)
        #pragma unroll
        for (int reg = 0; reg < 4; ++reg) {
            const int o = o0 + wv * 32 + io * 16 + quad * 4 + reg;
            const float b0 = bb[o];
            const size_t ro = ((size_t)b * CCH + o) * L + l0 + m;
            #pragma unroll
            for (int jl = 0; jl < 4; ++jl)
                y[ro + jl * 16] = f2bf(acc[io][jl][reg] + b0);
        }
}

// ---------------------------------------------------------------------------
// BatchNorm stats over bf16 tensor -> finalized scale/shift per channel
// ---------------------------------------------------------------------------
__device__ __forceinline__ void bn_stats_body(
    const ushort_t* y, const float* gamma, const float* beta,
    float* scale, float* shift, int c, int tid)
{
    float s = 0.f, s2 = 0.f;
    for (int b = 0; b < NB; ++b) {
        const uint4* p = (const uint4*)(y + ((size_t)b * CCH + c) * L);
        #pragma unroll
        for (int r = 0; r < 2; ++r) {
            uint4 v = p[r * 256 + tid];
            unsigned w[4] = {v.x, v.y, v.z, v.w};
            #pragma unroll
            for (int u = 0; u < 4; ++u) {
                float a = bflo(w[u]), bb = bfhi(w[u]);
                s  += a + bb;
                s2 += a * a + bb * bb;
            }
        }
    }
    #pragma unroll
    for (int off = 32; off > 0; off >>= 1) {
        s  += __shfl_down(s, off);
        s2 += __shfl_down(s2, off);
    }
    __shared__ float red[2][4];
    if ((tid & 63) == 0) { red[0][tid >> 6] = s; red[1][tid >> 6] = s2; }
    __syncthreads();
    if (tid == 0) {
        float S  = red[0][0] + red[0][1] + red[0][2] + red[0][3];
        float S2 = red[1][0] + red[1][1] + red[1][2] + red[1][3];
        const float invN = 1.f / (NB * (float)L);
        float mean = S * invN;
        float var  = S2 * invN - mean * mean;
        float rstd = rsqrtf(var + 1e-5f);
        float g = gamma[c];
        scale[c] = g * rstd;
        shift[c] = beta[c] - mean * g * rstd;
    }
}

__global__ __launch_bounds__(256) void bn_stats_k(
    const ushort_t* __restrict__ y, const float* __restrict__ gamma,
    const float* __restrict__ beta,
    float* __restrict__ scale, float* __restrict__ shift)
{
    bn_stats_body(y, gamma, beta, scale, shift, blockIdx.x, threadIdx.x);
}

// two tensors in one launch: blockIdx.x in [0,512)
__global__ __launch_bounds__(256) void bn_stats2_k(
    const ushort_t* __restrict__ y1, const float* __restrict__ g1, const float* __restrict__ be1,
    float* __restrict__ sc1, float* __restrict__ sh1,
    const ushort_t* __restrict__ y2, const float* __restrict__ g2, const float* __restrict__ be2,
    float* __restrict__ sc2, float* __restrict__ sh2)
{
    const int c = blockIdx.x & 255;
    if (blockIdx.x < 256) bn_stats_body(y1, g1, be1, sc1, sh1, c, threadIdx.x);
    else                  bn_stats_body(y2, g2, be2, sc2, sh2, c, threadIdx.x);
}

// ---------------------------------------------------------------------------
// Attention, two-phase, no atomics; bf16 y1/y2 inputs with precomputed
// scale/shift, bf16 pre output. LDS 64 KB -> 2 blocks/CU.
// ---------------------------------------------------------------------------
__global__ __launch_bounds__(512, 4) void attention_k(
    const float* __restrict__ x,
    const ushort_t* __restrict__ y1,
    const ushort_t* __restrict__ y2,
    const float* __restrict__ s1sc, const float* __restrict__ s1sh,
    const float* __restrict__ s2sc, const float* __restrict__ s2sh,
    ushort_t* __restrict__ pre)
{
    __shared__ unsigned sKQ[L];   // 16 KB: bf16 k (lo), q (hi)
    __shared__ float    sXv[L];   // 16 KB
    __shared__ uint2    sCI[L];   // 32 KB: {packed (kc,qc), bits(-ln S)}

    const int bc = blockIdx.x;
    const int tid = threadIdx.x;
    const int ch = bc & 255;
    const size_t off = (size_t)bc * L;

    const float sc1 = s1sc[ch], sh1 = s1sh[ch];
    const float sc2 = s2sc[ch], sh2 = s2sh[ch];

    const float4* x4 = (const float4*)(x + off);

    {
        uint4 ak = ((const uint4*)(y1 + off))[tid];
        uint4 aq = ((const uint4*)(y2 + off))[tid];
        unsigned wks[4] = {ak.x, ak.y, ak.z, ak.w};
        unsigned wqs[4] = {aq.x, aq.y, aq.z, aq.w};
        #pragma unroll
        for (int u = 0; u < 4; ++u) {
            float klo = fmaxf(fmaf(bflo(wks[u]), sc1, sh1), 0.f);
            float khi = fmaxf(fmaf(bfhi(wks[u]), sc1, sh1), 0.f);
            float qlo = fmaxf(fmaf(bflo(wqs[u]), sc2, sh2), 0.f);
            float qhi = fmaxf(fmaf(bfhi(wqs[u]), sc2, sh2), 0.f);
            sKQ[8 * tid + 2 * u]     = (unsigned)f2bf(klo) | ((unsigned)f2bf(qlo) << 16);
            sKQ[8 * tid + 2 * u + 1] = (unsigned)f2bf(khi) | ((unsigned)f2bf(qhi) << 16);
        }
        ((float4*)sXv)[2 * tid]     = x4[2 * tid];
        ((float4*)sXv)[2 * tid + 1] = x4[2 * tid + 1];
    }
    __syncthreads();

    // ---- Phase 1: per-window center + -ln(denominator) ----------------
    #pragma unroll
    for (int r = 0; r < 8; ++r) {
        const int lp = r * 512 + tid;
        const int base = 9 * lp;
        float kv[9], qv[9];
        unsigned cw = 0;
        #pragma unroll
        for (int j = 0; j < 9; ++j) {
            int f = base + j;
            int t = f >> 12;
            int l = f & 4095;
            int di = (t * 86) >> 8;     // t/3
            int dj = t - di * 3;
            int ii = (l >> 6) + di - 1;
            int jj = (l & 63) + dj - 1;
            bool ok = ((unsigned)ii < 64u) && ((unsigned)jj < 64u);
            int src = ((ii << 6) + jj) & 4095;
            unsigned w = sKQ[src];
            w = ok ? w : 0u;
            if (j == 4) cw = w;
            kv[j] = bflo(w);
            qv[j] = bfhi(w);
        }
        const float kc = kv[4], qc = qv[4];
        float s01 = __expf(kv[0] * qc + kc * qv[0]) + __expf(kv[1] * qc + kc * qv[1]);
        float s23 = __expf(kv[2] * qc + kc * qv[2]) + __expf(kv[3] * qc + kc * qv[3]);
        float s45 = __expf(kv[4] * qc + kc * qv[4]) + __expf(kv[5] * qc + kc * qv[5]);
        float s67 = __expf(kv[6] * qc + kc * qv[6]) + __expf(kv[7] * qc + kc * qv[7]);
        float s = ((s01 + s23) + (s45 + s67)) + __expf(kv[8] * qc + kc * qv[8]);
        uint2 ci;
        ci.x = cw;
        ci.y = __builtin_bit_cast(unsigned, -__logf(s));
        sCI[lp] = ci;
    }
    __syncthreads();

    // ---- Phase 2: per-output accumulate -------------------------------
    #pragma unroll
    for (int r = 0; r < 8; ++r) {
        const int l = r * 512 + tid;
        const int li = l >> 6, lj = l & 63;
        float acc = 0.f;
        #pragma unroll
        for (int t = 0; t < 9; ++t) {
            const int f = (t << 12) + l;
            const unsigned lp = (unsigned)f / 9u;           // magic-mul
            uint2 ci = sCI[lp];
            const float kc = bflo(ci.x), qc = bfhi(ci.x);
            const float cn = __builtin_bit_cast(float, ci.y);
            const int di = t / 3, dj = t % 3;               // constants
            int ii = li + di - 1;
            int jj = lj + dj - 1;
            bool ok = ((unsigned)ii < 64u) && ((unsigned)jj < 64u);
            int src = ((ii << 6) + jj) & 4095;
            unsigned w = sKQ[src];
            float xj = sXv[src];
            w  = ok ? w : 0u;
            xj = ok ? xj : 0.f;
            const float kj = bflo(w), qj = bfhi(w);
            float e = __expf(fmaf(kj, qc, fmaf(kc, qj, cn)));
            acc = fmaf(e, xj, acc);
        }
        pre[off + l] = f2bf(acc);
    }
}

// ---------------------------------------------------------------------------
// Final BN apply + ReLU: bf16 in, f32 out
// ---------------------------------------------------------------------------
__global__ __launch_bounds__(256) void bn_apply_k(
    const ushort_t* __restrict__ yf,
    const float* __restrict__ scale, const float* __restrict__ shift,
    float* __restrict__ out)
{
    const int i = blockIdx.x * 256 + threadIdx.x;   // uint4 index (8 elems)
    const int ch = (i >> 9) & 255;
    const float sc = scale[ch], sh = shift[ch];

    uint4 v = ((const uint4*)yf)[i];
    unsigned w[4] = {v.x, v.y, v.z, v.w};
    float4 o0, o1;
    o0.x = fmaxf(fmaf(bflo(w[0]), sc, sh), 0.f);
    o0.y = fmaxf(fmaf(bfhi(w[0]), sc, sh), 0.f);
    o0.z = fmaxf(fmaf(bflo(w[1]), sc, sh), 0.f);
    o0.w = fmaxf(fmaf(bfhi(w[1]), sc, sh), 0.f);
    o1.x = fmaxf(fmaf(bflo(w[2]), sc, sh), 0.f);
    o1.y = fmaxf(fmaf(bfhi(w[2]), sc, sh), 0.f);
    o1.z = fmaxf(fmaf(bflo(w[3]), sc, sh), 0.f);
    o1.w = fmaxf(fmaf(bfhi(w[3]), sc, sh), 0.f);
    ((float4*)out)[2 * i]     = o0;
    ((float4*)out)[2 * i + 1] = o1;
}

// ---------------------------------------------------------------------------
extern "C" void kernel_launch(void* const* d_in, const int* in_sizes, int n_in,
                              void* d_out, int out_size, void* d_ws, size_t ws_size,
                              hipStream_t stream) {
    const float* x   = (const float*)d_in[0];
    const float* w1  = (const float*)d_in[1];
    const float* b1  = (const float*)d_in[2];
    const float* g1  = (const float*)d_in[3];
    const float* be1 = (const float*)d_in[4];
    const float* w2  = (const float*)d_in[5];
    const float* b2  = (const float*)d_in[6];
    const float* g2  = (const float*)d_in[7];
    const float* be2 = (const float*)d_in[8];
    const float* wf  = (const float*)d_in[9];
    const float* bf  = (const float*)d_in[10];
    const float* gf  = (const float*)d_in[11];
    const float* bef = (const float*)d_in[12];
    float* out = (float*)d_out;

    const size_t NEL = (size_t)NB * CCH * L;       // 4194304
    ushort_t* y1b = (ushort_t*)d_ws;               // conv1 out (bf16); later yf
    ushort_t* y2b = y1b + NEL;                     // conv2 out (bf16); later pre
    float* st = (float*)(y2b + NEL);               // stats: 6 x 256
    float* s1sc = st,        *s1sh = st + 256;
    float* s2sc = st + 512,  *s2sh = st + 768;
    float* sfsc = st + 1024, *sfsh = st + 1280;

    dim3 gg(64, 2, 4);
    dual_gemm_k<<<gg, 256, 0, stream>>>(x, w1, b1, w2, b2, y1b, y2b);
    bn_stats2_k<<<512, 256, 0, stream>>>(y1b, g1, be1, s1sc, s1sh,
                                         y2b, g2, be2, s2sc, s2sh);
    attention_k<<<NB * CCH, 512, 0, stream>>>(x, y1b, y2b,
                                              s1sc, s1sh, s2sc, s2sh,
                                              /*pre=*/y2b);
    single_gemm_k<<<gg, 256, 0, stream>>>(/*pre=*/y2b, wf, bf, /*yf=*/y1b);
    bn_stats_k<<<256, 256, 0, stream>>>(y1b, gf, bef, sfsc, sfsh);
    bn_apply_k<<<(int)(NEL / 2048), 256, 0, stream>>>(y1b, sfsc, sfsh, out);
}

// Round 9
// 171.204 us; speedup vs baseline: 1.2932x; 1.0566x over previous
//
#include <hip/hip_runtime.h>

#define L 4096
#define CCH 256
#define NB 4
#define KP 40   // padded LDS row length (32 k + 8 pad) in bf16 elems; 80 B rows
#define GOF 72  // guarded-image front offset (alignment-friendly, >= 65)

typedef __attribute__((ext_vector_type(8))) short short8;
typedef __attribute__((ext_vector_type(4))) float f32x4;
typedef unsigned short ushort_t;

__device__ __forceinline__ unsigned short f2bf(float f) {
    unsigned u = __builtin_bit_cast(unsigned, f);
    u += 0x7FFF + ((u >> 16) & 1);
    return (unsigned short)(u >> 16);
}
__device__ __forceinline__ float bflo(unsigned w) {
    return __builtin_bit_cast(float, w << 16);
}
__device__ __forceinline__ float bfhi(unsigned w) {
    return __builtin_bit_cast(float, w & 0xFFFF0000u);
}
__device__ __forceinline__ float bfu(ushort_t h) {
    return __builtin_bit_cast(float, (unsigned)h << 16);
}

// ---------------------------------------------------------------------------
// Dual conv1x1 via bf16 MFMA; bf16 outputs, plain epilogue. (unchanged R8)
// ---------------------------------------------------------------------------
__global__ __launch_bounds__(256, 2) void dual_gemm_k(
    const float* __restrict__ x,
    const float* __restrict__ w1, const float* __restrict__ b1,
    const float* __restrict__ w2, const float* __restrict__ b2,
    ushort_t* __restrict__ y1, ushort_t* __restrict__ y2)
{
    __shared__ short sA1[128 * KP];
    __shared__ short sA2[128 * KP];
    __shared__ short sB [64 * KP];

    const int tid = threadIdx.x;
    const int l0 = blockIdx.x * 64;
    const int o0 = blockIdx.y * 128;
    const int b  = blockIdx.z;

    const int wv = tid >> 6;
    const int lane = tid & 63;
    const int m = lane & 15;
    const int quad = lane >> 4;

    const float* xb = x + (size_t)b * CCH * L;

    const int sl = tid & 63, soct = tid >> 6;
    const int sr = tid & 127, sh = tid >> 7;

    f32x4 acc1[2][4], acc2[2][4];
    #pragma unroll
    for (int io = 0; io < 2; ++io)
        #pragma unroll
        for (int jl = 0; jl < 4; ++jl) {
            acc1[io][jl] = (f32x4){0.f,0.f,0.f,0.f};
            acc2[io][jl] = (f32x4){0.f,0.f,0.f,0.f};
        }

    for (int s = 0; s < 8; ++s) {
        const int k0 = s * 32;
        __syncthreads();
        {
            const float* xs = xb + (size_t)(k0 + soct * 8) * L + l0 + sl;
            short8 v;
            #pragma unroll
            for (int j = 0; j < 8; ++j) v[j] = (short)f2bf(xs[(size_t)j * L]);
            *(short8*)&sB[sl * KP + soct * 8] = v;
        }
        {
            const float4* wp = (const float4*)&w1[(size_t)(o0 + sr) * CCH + k0 + sh * 16];
            float4 c0 = wp[0], c1 = wp[1], c2 = wp[2], c3 = wp[3];
            short8 p0 = {(short)f2bf(c0.x),(short)f2bf(c0.y),(short)f2bf(c0.z),(short)f2bf(c0.w),
                         (short)f2bf(c1.x),(short)f2bf(c1.y),(short)f2bf(c1.z),(short)f2bf(c1.w)};
            short8 p1 = {(short)f2bf(c2.x),(short)f2bf(c2.y),(short)f2bf(c2.z),(short)f2bf(c2.w),
                         (short)f2bf(c3.x),(short)f2bf(c3.y),(short)f2bf(c3.z),(short)f2bf(c3.w)};
            *(short8*)&sA1[sr * KP + sh * 16]     = p0;
            *(short8*)&sA1[sr * KP + sh * 16 + 8] = p1;
            const float4* wq = (const float4*)&w2[(size_t)(o0 + sr) * CCH + k0 + sh * 16];
            float4 d0 = wq[0], d1 = wq[1], d2 = wq[2], d3 = wq[3];
            short8 q0 = {(short)f2bf(d0.x),(short)f2bf(d0.y),(short)f2bf(d0.z),(short)f2bf(d0.w),
                         (short)f2bf(d1.x),(short)f2bf(d1.y),(short)f2bf(d1.z),(short)f2bf(d1.w)};
            short8 q1 = {(short)f2bf(d2.x),(short)f2bf(d2.y),(short)f2bf(d2.z),(short)f2bf(d2.w),
                         (short)f2bf(d3.x),(short)f2bf(d3.y),(short)f2bf(d3.z),(short)f2bf(d3.w)};
            *(short8*)&sA2[sr * KP + sh * 16]     = q0;
            *(short8*)&sA2[sr * KP + sh * 16 + 8] = q1;
        }
        __syncthreads();
        short8 a1[2], a2[2], bf[4];
        #pragma unroll
        for (int io = 0; io < 2; ++io) {
            a1[io] = *(const short8*)&sA1[(wv * 32 + io * 16 + m) * KP + quad * 8];
            a2[io] = *(const short8*)&sA2[(wv * 32 + io * 16 + m) * KP + quad * 8];
        }
        #pragma unroll
        for (int jl = 0; jl < 4; ++jl)
            bf[jl] = *(const short8*)&sB[(jl * 16 + m) * KP + quad * 8];
        #pragma unroll
        for (int io = 0; io < 2; ++io)
            #pragma unroll
            for (int jl = 0; jl < 4; ++jl) {
                acc1[io][jl] = __builtin_amdgcn_mfma_f32_16x16x32_bf16(a1[io], bf[jl], acc1[io][jl], 0, 0, 0);
                acc2[io][jl] = __builtin_amdgcn_mfma_f32_16x16x32_bf16(a2[io], bf[jl], acc2[io][jl], 0, 0, 0);
            }
    }

    #pragma unroll
    for (int io = 0; io < 2; ++io)
        #pragma unroll
        for (int reg = 0; reg < 4; ++reg) {
            const int o = o0 + wv * 32 + io * 16 + quad * 4 + reg;
            const float bb1 = b1[o], bb2 = b2[o];
            const size_t ro = ((size_t)b * CCH + o) * L + l0 + m;
            #pragma unroll
            for (int jl = 0; jl < 4; ++jl) {
                y1[ro + jl * 16] = f2bf(acc1[io][jl][reg] + bb1);
                y2[ro + jl * 16] = f2bf(acc2[io][jl][reg] + bb2);
            }
        }
}

// ---------------------------------------------------------------------------
// Single conv1x1 via bf16 MFMA (unchanged R8)
// ---------------------------------------------------------------------------
__global__ __launch_bounds__(256, 2) void single_gemm_k(
    const ushort_t* __restrict__ x,
    const float* __restrict__ w, const float* __restrict__ bb,
    ushort_t* __restrict__ y)
{
    __shared__ short sA[128 * KP];
    __shared__ short sB[64 * KP];

    const int tid = threadIdx.x;
    const int l0 = blockIdx.x * 64;
    const int o0 = blockIdx.y * 128;
    const int b  = blockIdx.z;

    const int wv = tid >> 6;
    const int lane = tid & 63;
    const int m = lane & 15;
    const int quad = lane >> 4;

    const ushort_t* xb = x + (size_t)b * CCH * L;

    const int sl = tid & 63, soct = tid >> 6;
    const int sr = tid & 127, sh = tid >> 7;

    f32x4 acc[2][4];
    #pragma unroll
    for (int io = 0; io < 2; ++io)
        #pragma unroll
        for (int jl = 0; jl < 4; ++jl)
            acc[io][jl] = (f32x4){0.f,0.f,0.f,0.f};

    for (int s = 0; s < 8; ++s) {
        const int k0 = s * 32;
        __syncthreads();
        {
            const ushort_t* xs = xb + (size_t)(k0 + soct * 8) * L + l0 + sl;
            short8 v;
            #pragma unroll
            for (int j = 0; j < 8; ++j) v[j] = (short)xs[(size_t)j * L];
            *(short8*)&sB[sl * KP + soct * 8] = v;
        }
        {
            const float4* wp = (const float4*)&w[(size_t)(o0 + sr) * CCH + k0 + sh * 16];
            float4 c0 = wp[0], c1 = wp[1], c2 = wp[2], c3 = wp[3];
            short8 p0 = {(short)f2bf(c0.x),(short)f2bf(c0.y),(short)f2bf(c0.z),(short)f2bf(c0.w),
                         (short)f2bf(c1.x),(short)f2bf(c1.y),(short)f2bf(c1.z),(short)f2bf(c1.w)};
            short8 p1 = {(short)f2bf(c2.x),(short)f2bf(c2.y),(short)f2bf(c2.z),(short)f2bf(c2.w),
                         (short)f2bf(c3.x),(short)f2bf(c3.y),(short)f2bf(c3.z),(short)f2bf(c3.w)};
            *(short8*)&sA[sr * KP + sh * 16]     = p0;
            *(short8*)&sA[sr * KP + sh * 16 + 8] = p1;
        }
        __syncthreads();
        short8 a[2], bf[4];
        #pragma unroll
        for (int io = 0; io < 2; ++io)
            a[io] = *(const short8*)&sA[(wv * 32 + io * 16 + m) * KP + quad * 8];
        #pragma unroll
        for (int jl = 0; jl < 4; ++jl)
            bf[jl] = *(const short8*)&sB[(jl * 16 + m) * KP + quad * 8];
        #pragma unroll
        for (int io = 0; io < 2; ++io)
            #pragma unroll
            for (int jl = 0; jl < 4; ++jl)
                acc[io][jl] = __builtin_amdgcn_mfma_f32_16x16x32_bf16(a[io], bf[jl], acc[io][jl], 0, 0, 0);
    }

    #pragma unroll
    for (int io = 0; io < 2; ++io)
        #pragma unroll
        for (int reg = 0; reg < 4; ++reg) {
            const int o = o0 + wv * 32 + io * 16 + quad * 4 + reg;
            const float b0 = bb[o];
            const size_t ro = ((size_t)b * CCH + o) * L + l0 + m;
            #pragma unroll
            for (int jl = 0; jl < 4; ++jl)
                y[ro + jl * 16] = f2bf(acc[io][jl][reg] + b0);
        }
}

// ---------------------------------------------------------------------------
// BatchNorm stats over bf16 tensor -> finalized scale/shift (unchanged R8)
// ---------------------------------------------------------------------------
__device__ __forceinline__ void bn_stats_body(
    const ushort_t* y, const float* gamma, const float* beta,
    float* scale, float* shift, int c, int tid)
{
    float s = 0.f, s2 = 0.f;
    for (int b = 0; b < NB; ++b) {
        const uint4* p = (const uint4*)(y + ((size_t)b * CCH + c) * L);
        #pragma unroll
        for (int r = 0; r < 2; ++r) {
            uint4 v = p[r * 256 + tid];
            unsigned w[4] = {v.x, v.y, v.z, v.w};
            #pragma unroll
            for (int u = 0; u < 4; ++u) {
                float a = bflo(w[u]), bb = bfhi(w[u]);
                s  += a + bb;
                s2 += a * a + bb * bb;
            }
        }
    }
    #pragma unroll
    for (int off = 32; off > 0; off >>= 1) {
        s  += __shfl_down(s, off);
        s2 += __shfl_down(s2, off);
    }
    __shared__ float red[2][4];
    if ((tid & 63) == 0) { red[0][tid >> 6] = s; red[1][tid >> 6] = s2; }
    __syncthreads();
    if (tid == 0) {
        float S  = red[0][0] + red[0][1] + red[0][2] + red[0][3];
        float S2 = red[1][0] + red[1][1] + red[1][2] + red[1][3];
        const float invN = 1.f / (NB * (float)L);
        float mean = S * invN;
        float var  = S2 * invN - mean * mean;
        float rstd = rsqrtf(var + 1e-5f);
        float g = gamma[c];
        scale[c] = g * rstd;
        shift[c] = beta[c] - mean * g * rstd;
    }
}

__global__ __launch_bounds__(256) void bn_stats_k(
    const ushort_t* __restrict__ y, const float* __restrict__ gamma,
    const float* __restrict__ beta,
    float* __restrict__ scale, float* __restrict__ shift)
{
    bn_stats_body(y, gamma, beta, scale, shift, blockIdx.x, threadIdx.x);
}

__global__ __launch_bounds__(256) void bn_stats2_k(
    const ushort_t* __restrict__ y1, const float* __restrict__ g1, const float* __restrict__ be1,
    float* __restrict__ sc1, float* __restrict__ sh1,
    const ushort_t* __restrict__ y2, const float* __restrict__ g2, const float* __restrict__ be2,
    float* __restrict__ sc2, float* __restrict__ sh2)
{
    const int c = blockIdx.x & 255;
    if (blockIdx.x < 256) bn_stats_body(y1, g1, be1, sc1, sh1, c, threadIdx.x);
    else                  bn_stats_body(y2, g2, be2, sc2, sh2, c, threadIdx.x);
}

// ---------------------------------------------------------------------------
// Attention v3: guard-row LDS images (zero padding rows -> no row masks),
// run-based gathers with immediate offsets (no per-read address VALU),
// conflict-free lane-stride-1 access. Two-phase, no atomics.
// LDS: sKQg 16.9K + sXg 8.5K + sCI 32.8K = 58.2 KB -> 2 blocks/CU.
// ---------------------------------------------------------------------------
__global__ __launch_bounds__(512, 4) void attention_k(
    const float* __restrict__ x,
    const ushort_t* __restrict__ y1,
    const ushort_t* __restrict__ y2,
    const float* __restrict__ s1sc, const float* __restrict__ s1sh,
    const float* __restrict__ s2sc, const float* __restrict__ s2sh,
    ushort_t* __restrict__ pre)
{
    __shared__ unsigned sKQg[4240];   // [GOF+s] = packed bf16 (k,q); guards zero
    __shared__ ushort_t sXg [4240];   // [GOF+s] = bf16 x; guards zero
    __shared__ uint2    sCI [L];      // {packed (kc,qc), bits(-ln S)} per window

    const int bc = blockIdx.x;
    const int tid = threadIdx.x;
    const int ch = bc & 255;
    const size_t off = (size_t)bc * L;

    const float sc1 = s1sc[ch], sh1 = s1sh[ch];
    const float sc2 = s2sc[ch], sh2 = s2sh[ch];

    // ---- stage + guards ----------------------------------------------
    if (tid < GOF)  { sKQg[tid] = 0; sXg[tid] = 0; }
    if (tid < 72)   { sKQg[GOF + 4096 + tid] = 0; sXg[GOF + 4096 + tid] = 0; }
    {
        uint4 ak = ((const uint4*)(y1 + off))[tid];
        uint4 aq = ((const uint4*)(y2 + off))[tid];
        float4 xa = ((const float4*)(x + off))[2 * tid];
        float4 xb = ((const float4*)(x + off))[2 * tid + 1];
        unsigned wk[4] = {ak.x, ak.y, ak.z, ak.w};
        unsigned wq[4] = {aq.x, aq.y, aq.z, aq.w};
        unsigned kq[8];
        #pragma unroll
        for (int u = 0; u < 4; ++u) {
            float klo = fmaxf(fmaf(bflo(wk[u]), sc1, sh1), 0.f);
            float khi = fmaxf(fmaf(bfhi(wk[u]), sc1, sh1), 0.f);
            float qlo = fmaxf(fmaf(bflo(wq[u]), sc2, sh2), 0.f);
            float qhi = fmaxf(fmaf(bfhi(wq[u]), sc2, sh2), 0.f);
            kq[2*u]   = (unsigned)f2bf(klo) | ((unsigned)f2bf(qlo) << 16);
            kq[2*u+1] = (unsigned)f2bf(khi) | ((unsigned)f2bf(qhi) << 16);
        }
        *(uint4*)&sKQg[GOF + 8 * tid]     = make_uint4(kq[0], kq[1], kq[2], kq[3]);
        *(uint4*)&sKQg[GOF + 8 * tid + 4] = make_uint4(kq[4], kq[5], kq[6], kq[7]);
        float xv[8] = {xa.x, xa.y, xa.z, xa.w, xb.x, xb.y, xb.z, xb.w};
        unsigned xp[4];
        #pragma unroll
        for (int u = 0; u < 4; ++u)
            xp[u] = (unsigned)f2bf(xv[2*u]) | ((unsigned)f2bf(xv[2*u+1]) << 16);
        *(uint4*)&sXg[GOF + 8 * tid] = make_uint4(xp[0], xp[1], xp[2], xp[3]);
    }
    __syncthreads();

    // ---- Phase 1: per-window center + -ln(denominator) ----------------
    // window lp = r*512 + tid; its 9 taps are flat-consecutive (same unfold
    // tap t) except the 8 windows straddling a 4096 boundary.
    {
        const int fbase = 9 * tid;
        #pragma unroll
        for (int r = 0; r < 8; ++r) {
            const int f  = fbase + 4608 * r;
            const int t  = f >> 12;
            const int fl = f & 4095;
            unsigned wv[9];
            if (fl < 4088) {                       // fast path: single tap t
                const int di = (t * 86) >> 8;
                const int dj = t - 3 * di;
                const int cbad = (dj == 0) ? 0 : ((dj == 2) ? 63 : 99);
                const int base = fl + (di << 6) + dj - 65 + GOF;
                #pragma unroll
                for (int j = 0; j < 9; ++j) wv[j] = sKQg[base + j];
                #pragma unroll
                for (int j = 0; j < 9; ++j) {
                    int c = (fl + j) & 63;
                    wv[j] = (c == cbad) ? 0u : wv[j];
                }
            } else {                               // straddle: generic decode
                #pragma unroll
                for (int j = 0; j < 9; ++j) {
                    int fj = f + j;
                    int tj = fj >> 12, lj = fj & 4095;
                    int dij = (tj * 86) >> 8, djj = tj - 3 * dij;
                    int idx = lj + (dij << 6) + djj - 65 + GOF;
                    unsigned wr = sKQg[idx];
                    int c = lj & 63;
                    int cb = (djj == 0) ? 0 : ((djj == 2) ? 63 : 99);
                    wv[j] = (c == cb) ? 0u : wr;
                }
            }
            const unsigned cw = wv[4];
            const float kc = bflo(cw), qc = bfhi(cw);
            float e0 = __expf(bflo(wv[0]) * qc + kc * bfhi(wv[0]));
            float e1 = __expf(bflo(wv[1]) * qc + kc * bfhi(wv[1]));
            float e2 = __expf(bflo(wv[2]) * qc + kc * bfhi(wv[2]));
            float e3 = __expf(bflo(wv[3]) * qc + kc * bfhi(wv[3]));
            float e4 = __expf(bflo(wv[4]) * qc + kc * bfhi(wv[4]));
            float e5 = __expf(bflo(wv[5]) * qc + kc * bfhi(wv[5]));
            float e6 = __expf(bflo(wv[6]) * qc + kc * bfhi(wv[6]));
            float e7 = __expf(bflo(wv[7]) * qc + kc * bfhi(wv[7]));
            float e8 = __expf(bflo(wv[8]) * qc + kc * bfhi(wv[8]));
            float s = (((e0 + e1) + (e2 + e3)) + ((e4 + e5) + (e6 + e7))) + e8;
            uint2 ci;
            ci.x = cw;
            ci.y = __builtin_bit_cast(unsigned, -__logf(s));
            sCI[r * 512 + tid] = ci;
        }
    }
    __syncthreads();

    // ---- Phase 2: per-output accumulate; outputs l = r*512 + tid ------
    {
        const int c0 = tid & 63;                   // column, same for all r
        float acc[8];
        #pragma unroll
        for (int r = 0; r < 8; ++r) acc[r] = 0.f;

        #pragma unroll
        for (int t = 0; t < 9; ++t) {
            const int di = t / 3, dj = t % 3;      // compile-time
            const int base = tid + (di << 6) + dj - 65 + GOF;
            const bool colbad = (dj == 0) ? (c0 == 0) : ((dj == 2) ? (c0 == 63) : false);
            const int ft = (t << 12) + tid;
            #pragma unroll
            for (int r = 0; r < 8; ++r) {
                const int f = ft + 512 * r;
                const unsigned lp = (unsigned)f / 9u;     // magic-mul
                uint2 ci = sCI[lp];
                const float kc = bflo(ci.x), qc = bfhi(ci.x);
                const float cn = __builtin_bit_cast(float, ci.y);
                unsigned wv = sKQg[base + 512 * r];       // imm-offset read
                float xj = bfu(sXg[base + 512 * r]);      // imm-offset read
                xj = colbad ? 0.f : xj;
                float e = __expf(fmaf(bflo(wv), qc, fmaf(kc, bfhi(wv), cn)));
                acc[r] = fmaf(e, xj, acc[r]);
            }
        }
        #pragma unroll
        for (int r = 0; r < 8; ++r)
            pre[off + r * 512 + tid] = f2bf(acc[r]);
    }
}

// ---------------------------------------------------------------------------
// Final BN apply + ReLU: bf16 in, f32 out (unchanged R8)
// ---------------------------------------------------------------------------
__global__ __launch_bounds__(256) void bn_apply_k(
    const ushort_t* __restrict__ yf,
    const float* __restrict__ scale, const float* __restrict__ shift,
    float* __restrict__ out)
{
    const int i = blockIdx.x * 256 + threadIdx.x;   // uint4 index (8 elems)
    const int ch = (i >> 9) & 255;
    const float sc = scale[ch], sh = shift[ch];

    uint4 v = ((const uint4*)yf)[i];
    unsigned w[4] = {v.x, v.y, v.z, v.w};
    float4 o0, o1;
    o0.x = fmaxf(fmaf(bflo(w[0]), sc, sh), 0.f);
    o0.y = fmaxf(fmaf(bfhi(w[0]), sc, sh), 0.f);
    o0.z = fmaxf(fmaf(bflo(w[1]), sc, sh), 0.f);
    o0.w = fmaxf(fmaf(bfhi(w[1]), sc, sh), 0.f);
    o1.x = fmaxf(fmaf(bflo(w[2]), sc, sh), 0.f);
    o1.y = fmaxf(fmaf(bfhi(w[2]), sc, sh), 0.f);
    o1.z = fmaxf(fmaf(bflo(w[3]), sc, sh), 0.f);
    o1.w = fmaxf(fmaf(bfhi(w[3]), sc, sh), 0.f);
    ((float4*)out)[2 * i]     = o0;
    ((float4*)out)[2 * i + 1] = o1;
}

// ---------------------------------------------------------------------------
extern "C" void kernel_launch(void* const* d_in, const int* in_sizes, int n_in,
                              void* d_out, int out_size, void* d_ws, size_t ws_size,
                              hipStream_t stream) {
    const float* x   = (const float*)d_in[0];
    const float* w1  = (const float*)d_in[1];
    const float* b1  = (const float*)d_in[2];
    const float* g1  = (const float*)d_in[3];
    const float* be1 = (const float*)d_in[4];
    const float* w2  = (const float*)d_in[5];
    const float* b2  = (const float*)d_in[6];
    const float* g2  = (const float*)d_in[7];
    const float* be2 = (const float*)d_in[8];
    const float* wf  = (const float*)d_in[9];
    const float* bf  = (const float*)d_in[10];
    const float* gf  = (const float*)d_in[11];
    const float* bef = (const float*)d_in[12];
    float* out = (float*)d_out;

    const size_t NEL = (size_t)NB * CCH * L;       // 4194304
    ushort_t* y1b = (ushort_t*)d_ws;               // conv1 out (bf16); later yf
    ushort_t* y2b = y1b + NEL;                     // conv2 out (bf16); later pre
    float* st = (float*)(y2b + NEL);               // stats: 6 x 256
    float* s1sc = st,        *s1sh = st + 256;
    float* s2sc = st + 512,  *s2sh = st + 768;
    float* sfsc = st + 1024, *sfsh = st + 1280;

    dim3 gg(64, 2, 4);
    dual_gemm_k<<<gg, 256, 0, stream>>>(x, w1, b1, w2, b2, y1b, y2b);
    bn_stats2_k<<<512, 256, 0, stream>>>(y1b, g1, be1, s1sc, s1sh,
                                         y2b, g2, be2, s2sc, s2sh);
    attention_k<<<NB * CCH, 512, 0, stream>>>(x, y1b, y2b,
                                              s1sc, s1sh, s2sc, s2sh,
                                              /*pre=*/y2b);
    single_gemm_k<<<gg, 256, 0, stream>>>(/*pre=*/y2b, wf, bf, /*yf=*/y1b);
    bn_stats_k<<<256, 256, 0, stream>>>(y1b, gf, bef, sfsc, sfsh);
    bn_apply_k<<<(int)(NEL / 2048), 256, 0, stream>>>(y1b, sfsc, sfsh, out);
}

// Round 10
// 161.926 us; speedup vs baseline: 1.3673x; 1.0573x over previous
//
#include <hip/hip_runtime.h>

#define L 4096
#define CCH 256
#define NB 4
#define KP 40   // padded LDS row length (32 k + 8 pad) in bf16 elems; 80 B rows
#define GOF 72  // guarded-image front offset (alignment-friendly, >= 65)

typedef __attribute__((ext_vector_type(8))) short short8;
typedef __attribute__((ext_vector_type(4))) float f32x4;
typedef unsigned short ushort_t;

__device__ __forceinline__ unsigned short f2bf(float f) {
    unsigned u = __builtin_bit_cast(unsigned, f);
    u += 0x7FFF + ((u >> 16) & 1);
    return (unsigned short)(u >> 16);
}
__device__ __forceinline__ float bflo(unsigned w) {
    return __builtin_bit_cast(float, w << 16);
}
__device__ __forceinline__ float bfhi(unsigned w) {
    return __builtin_bit_cast(float, w & 0xFFFF0000u);
}
__device__ __forceinline__ float bfu(ushort_t h) {
    return __builtin_bit_cast(float, (unsigned)h << 16);
}

// ---------------------------------------------------------------------------
// One-time weight conversion: w1|w2|wf (each 256x256 f32) -> bf16
// 192 blocks x 256 threads, 4 floats/thread.
// ---------------------------------------------------------------------------
__global__ __launch_bounds__(256) void wcvt_k(
    const float* __restrict__ w1, const float* __restrict__ w2,
    const float* __restrict__ wf,
    ushort_t* __restrict__ wb1, ushort_t* __restrict__ wb2,
    ushort_t* __restrict__ wbf)
{
    const int mb = blockIdx.x >> 6;          // 0..2: which matrix
    const int i  = (blockIdx.x & 63) * 256 + threadIdx.x;   // float4 index
    const float* src = (mb == 0) ? w1 : (mb == 1) ? w2 : wf;
    ushort_t*    dst = (mb == 0) ? wb1 : (mb == 1) ? wb2 : wbf;
    float4 v = ((const float4*)src)[i];
    uint2 p;
    p.x = (unsigned)f2bf(v.x) | ((unsigned)f2bf(v.y) << 16);
    p.y = (unsigned)f2bf(v.z) | ((unsigned)f2bf(v.w) << 16);
    ((uint2*)dst)[i] = p;
}

// ---------------------------------------------------------------------------
// Dual conv1x1 via bf16 MFMA; weights pre-converted to bf16 (pure copy
// staging), bf16 outputs.
// ---------------------------------------------------------------------------
__global__ __launch_bounds__(256, 2) void dual_gemm_k(
    const float* __restrict__ x,
    const ushort_t* __restrict__ wb1, const float* __restrict__ b1,
    const ushort_t* __restrict__ wb2, const float* __restrict__ b2,
    ushort_t* __restrict__ y1, ushort_t* __restrict__ y2)
{
    __shared__ short sA1[128 * KP];
    __shared__ short sA2[128 * KP];
    __shared__ short sB [64 * KP];

    const int tid = threadIdx.x;
    const int l0 = blockIdx.x * 64;
    const int o0 = blockIdx.y * 128;
    const int b  = blockIdx.z;

    const int wv = tid >> 6;
    const int lane = tid & 63;
    const int m = lane & 15;
    const int quad = lane >> 4;

    const float* xb = x + (size_t)b * CCH * L;

    const int sl = tid & 63, soct = tid >> 6;
    const int sr = tid & 127, sh = tid >> 7;

    f32x4 acc1[2][4], acc2[2][4];
    #pragma unroll
    for (int io = 0; io < 2; ++io)
        #pragma unroll
        for (int jl = 0; jl < 4; ++jl) {
            acc1[io][jl] = (f32x4){0.f,0.f,0.f,0.f};
            acc2[io][jl] = (f32x4){0.f,0.f,0.f,0.f};
        }

    for (int s = 0; s < 8; ++s) {
        const int k0 = s * 32;
        __syncthreads();
        {
            const float* xs = xb + (size_t)(k0 + soct * 8) * L + l0 + sl;
            short8 v;
            #pragma unroll
            for (int j = 0; j < 8; ++j) v[j] = (short)f2bf(xs[(size_t)j * L]);
            *(short8*)&sB[sl * KP + soct * 8] = v;
        }
        {
            const uint4* wp = (const uint4*)&wb1[(size_t)(o0 + sr) * CCH + k0 + sh * 16];
            uint4 p0 = wp[0], p1 = wp[1];
            *(uint4*)&sA1[sr * KP + sh * 16]     = p0;
            *(uint4*)&sA1[sr * KP + sh * 16 + 8] = p1;
            const uint4* wq = (const uint4*)&wb2[(size_t)(o0 + sr) * CCH + k0 + sh * 16];
            uint4 q0 = wq[0], q1 = wq[1];
            *(uint4*)&sA2[sr * KP + sh * 16]     = q0;
            *(uint4*)&sA2[sr * KP + sh * 16 + 8] = q1;
        }
        __syncthreads();
        short8 a1[2], a2[2], bf[4];
        #pragma unroll
        for (int io = 0; io < 2; ++io) {
            a1[io] = *(const short8*)&sA1[(wv * 32 + io * 16 + m) * KP + quad * 8];
            a2[io] = *(const short8*)&sA2[(wv * 32 + io * 16 + m) * KP + quad * 8];
        }
        #pragma unroll
        for (int jl = 0; jl < 4; ++jl)
            bf[jl] = *(const short8*)&sB[(jl * 16 + m) * KP + quad * 8];
        #pragma unroll
        for (int io = 0; io < 2; ++io)
            #pragma unroll
            for (int jl = 0; jl < 4; ++jl) {
                acc1[io][jl] = __builtin_amdgcn_mfma_f32_16x16x32_bf16(a1[io], bf[jl], acc1[io][jl], 0, 0, 0);
                acc2[io][jl] = __builtin_amdgcn_mfma_f32_16x16x32_bf16(a2[io], bf[jl], acc2[io][jl], 0, 0, 0);
            }
    }

    #pragma unroll
    for (int io = 0; io < 2; ++io)
        #pragma unroll
        for (int reg = 0; reg < 4; ++reg) {
            const int o = o0 + wv * 32 + io * 16 + quad * 4 + reg;
            const float bb1 = b1[o], bb2 = b2[o];
            const size_t ro = ((size_t)b * CCH + o) * L + l0 + m;
            #pragma unroll
            for (int jl = 0; jl < 4; ++jl) {
                y1[ro + jl * 16] = f2bf(acc1[io][jl][reg] + bb1);
                y2[ro + jl * 16] = f2bf(acc2[io][jl][reg] + bb2);
            }
        }
}

// ---------------------------------------------------------------------------
// Single conv1x1 via bf16 MFMA: bf16 input (pre), bf16 weights, bf16 output
// ---------------------------------------------------------------------------
__global__ __launch_bounds__(256, 2) void single_gemm_k(
    const ushort_t* __restrict__ x,
    const ushort_t* __restrict__ wb, const float* __restrict__ bb,
    ushort_t* __restrict__ y)
{
    __shared__ short sA[128 * KP];
    __shared__ short sB[64 * KP];

    const int tid = threadIdx.x;
    const int l0 = blockIdx.x * 64;
    const int o0 = blockIdx.y * 128;
    const int b  = blockIdx.z;

    const int wv = tid >> 6;
    const int lane = tid & 63;
    const int m = lane & 15;
    const int quad = lane >> 4;

    const ushort_t* xb = x + (size_t)b * CCH * L;

    const int sl = tid & 63, soct = tid >> 6;
    const int sr = tid & 127, sh = tid >> 7;

    f32x4 acc[2][4];
    #pragma unroll
    for (int io = 0; io < 2; ++io)
        #pragma unroll
        for (int jl = 0; jl < 4; ++jl)
            acc[io][jl] = (f32x4){0.f,0.f,0.f,0.f};

    for (int s = 0; s < 8; ++s) {
        const int k0 = s * 32;
        __syncthreads();
        {
            const ushort_t* xs = xb + (size_t)(k0 + soct * 8) * L + l0 + sl;
            short8 v;
            #pragma unroll
            for (int j = 0; j < 8; ++j) v[j] = (short)xs[(size_t)j * L];
            *(short8*)&sB[sl * KP + soct * 8] = v;
        }
        {
            const uint4* wp = (const uint4*)&wb[(size_t)(o0 + sr) * CCH + k0 + sh * 16];
            uint4 p0 = wp[0], p1 = wp[1];
            *(uint4*)&sA[sr * KP + sh * 16]     = p0;
            *(uint4*)&sA[sr * KP + sh * 16 + 8] = p1;
        }
        __syncthreads();
        short8 a[2], bf[4];
        #pragma unroll
        for (int io = 0; io < 2; ++io)
            a[io] = *(const short8*)&sA[(wv * 32 + io * 16 + m) * KP + quad * 8];
        #pragma unroll
        for (int jl = 0; jl < 4; ++jl)
            bf[jl] = *(const short8*)&sB[(jl * 16 + m) * KP + quad * 8];
        #pragma unroll
        for (int io = 0; io < 2; ++io)
            #pragma unroll
            for (int jl = 0; jl < 4; ++jl)
                acc[io][jl] = __builtin_amdgcn_mfma_f32_16x16x32_bf16(a[io], bf[jl], acc[io][jl], 0, 0, 0);
    }

    #pragma unroll
    for (int io = 0; io < 2; ++io)
        #pragma unroll
        for (int reg = 0; reg < 4; ++reg) {
            const int o = o0 + wv * 32 + io * 16 + quad * 4 + reg;
            const float b0 = bb[o];
            const size_t ro = ((size_t)b * CCH + o) * L + l0 + m;
            #pragma unroll
            for (int jl = 0; jl < 4; ++jl)
                y[ro + jl * 16] = f2bf(acc[io][jl][reg] + b0);
        }
}

// ---------------------------------------------------------------------------
// BatchNorm stats over bf16 tensor -> finalized scale/shift (unchanged)
// ---------------------------------------------------------------------------
__device__ __forceinline__ void bn_stats_body(
    const ushort_t* y, const float* gamma, const float* beta,
    float* scale, float* shift, int c, int tid)
{
    float s = 0.f, s2 = 0.f;
    for (int b = 0; b < NB; ++b) {
        const uint4* p = (const uint4*)(y + ((size_t)b * CCH + c) * L);
        #pragma unroll
        for (int r = 0; r < 2; ++r) {
            uint4 v = p[r * 256 + tid];
            unsigned w[4] = {v.x, v.y, v.z, v.w};
            #pragma unroll
            for (int u = 0; u < 4; ++u) {
                float a = bflo(w[u]), bb = bfhi(w[u]);
                s  += a + bb;
                s2 += a * a + bb * bb;
            }
        }
    }
    #pragma unroll
    for (int off = 32; off > 0; off >>= 1) {
        s  += __shfl_down(s, off);
        s2 += __shfl_down(s2, off);
    }
    __shared__ float red[2][4];
    if ((tid & 63) == 0) { red[0][tid >> 6] = s; red[1][tid >> 6] = s2; }
    __syncthreads();
    if (tid == 0) {
        float S  = red[0][0] + red[0][1] + red[0][2] + red[0][3];
        float S2 = red[1][0] + red[1][1] + red[1][2] + red[1][3];
        const float invN = 1.f / (NB * (float)L);
        float mean = S * invN;
        float var  = S2 * invN - mean * mean;
        float rstd = rsqrtf(var + 1e-5f);
        float g = gamma[c];
        scale[c] = g * rstd;
        shift[c] = beta[c] - mean * g * rstd;
    }
}

__global__ __launch_bounds__(256) void bn_stats_k(
    const ushort_t* __restrict__ y, const float* __restrict__ gamma,
    const float* __restrict__ beta,
    float* __restrict__ scale, float* __restrict__ shift)
{
    bn_stats_body(y, gamma, beta, scale, shift, blockIdx.x, threadIdx.x);
}

__global__ __launch_bounds__(256) void bn_stats2_k(
    const ushort_t* __restrict__ y1, const float* __restrict__ g1, const float* __restrict__ be1,
    float* __restrict__ sc1, float* __restrict__ sh1,
    const ushort_t* __restrict__ y2, const float* __restrict__ g2, const float* __restrict__ be2,
    float* __restrict__ sc2, float* __restrict__ sh2)
{
    const int c = blockIdx.x & 255;
    if (blockIdx.x < 256) bn_stats_body(y1, g1, be1, sc1, sh1, c, threadIdx.x);
    else                  bn_stats_body(y2, g2, be2, sc2, sh2, c, threadIdx.x);
}

// ---------------------------------------------------------------------------
// Attention v3 (unchanged R9): guard-row LDS images, run-based gathers.
// ---------------------------------------------------------------------------
__global__ __launch_bounds__(512, 4) void attention_k(
    const float* __restrict__ x,
    const ushort_t* __restrict__ y1,
    const ushort_t* __restrict__ y2,
    const float* __restrict__ s1sc, const float* __restrict__ s1sh,
    const float* __restrict__ s2sc, const float* __restrict__ s2sh,
    ushort_t* __restrict__ pre)
{
    __shared__ unsigned sKQg[4240];   // [GOF+s] = packed bf16 (k,q); guards zero
    __shared__ ushort_t sXg [4240];   // [GOF+s] = bf16 x; guards zero
    __shared__ uint2    sCI [L];      // {packed (kc,qc), bits(-ln S)} per window

    const int bc = blockIdx.x;
    const int tid = threadIdx.x;
    const int ch = bc & 255;
    const size_t off = (size_t)bc * L;

    const float sc1 = s1sc[ch], sh1 = s1sh[ch];
    const float sc2 = s2sc[ch], sh2 = s2sh[ch];

    // ---- stage + guards ----------------------------------------------
    if (tid < GOF)  { sKQg[tid] = 0; sXg[tid] = 0; }
    if (tid < 72)   { sKQg[GOF + 4096 + tid] = 0; sXg[GOF + 4096 + tid] = 0; }
    {
        uint4 ak = ((const uint4*)(y1 + off))[tid];
        uint4 aq = ((const uint4*)(y2 + off))[tid];
        float4 xa = ((const float4*)(x + off))[2 * tid];
        float4 xb = ((const float4*)(x + off))[2 * tid + 1];
        unsigned wk[4] = {ak.x, ak.y, ak.z, ak.w};
        unsigned wq[4] = {aq.x, aq.y, aq.z, aq.w};
        unsigned kq[8];
        #pragma unroll
        for (int u = 0; u < 4; ++u) {
            float klo = fmaxf(fmaf(bflo(wk[u]), sc1, sh1), 0.f);
            float khi = fmaxf(fmaf(bfhi(wk[u]), sc1, sh1), 0.f);
            float qlo = fmaxf(fmaf(bflo(wq[u]), sc2, sh2), 0.f);
            float qhi = fmaxf(fmaf(bfhi(wq[u]), sc2, sh2), 0.f);
            kq[2*u]   = (unsigned)f2bf(klo) | ((unsigned)f2bf(qlo) << 16);
            kq[2*u+1] = (unsigned)f2bf(khi) | ((unsigned)f2bf(qhi) << 16);
        }
        *(uint4*)&sKQg[GOF + 8 * tid]     = make_uint4(kq[0], kq[1], kq[2], kq[3]);
        *(uint4*)&sKQg[GOF + 8 * tid + 4] = make_uint4(kq[4], kq[5], kq[6], kq[7]);
        float xv[8] = {xa.x, xa.y, xa.z, xa.w, xb.x, xb.y, xb.z, xb.w};
        unsigned xp[4];
        #pragma unroll
        for (int u = 0; u < 4; ++u)
            xp[u] = (unsigned)f2bf(xv[2*u]) | ((unsigned)f2bf(xv[2*u+1]) << 16);
        *(uint4*)&sXg[GOF + 8 * tid] = make_uint4(xp[0], xp[1], xp[2], xp[3]);
    }
    __syncthreads();

    // ---- Phase 1: per-window center + -ln(denominator) ----------------
    {
        const int fbase = 9 * tid;
        #pragma unroll
        for (int r = 0; r < 8; ++r) {
            const int f  = fbase + 4608 * r;
            const int t  = f >> 12;
            const int fl = f & 4095;
            unsigned wv[9];
            if (fl < 4088) {                       // fast path: single tap t
                const int di = (t * 86) >> 8;
                const int dj = t - 3 * di;
                const int cbad = (dj == 0) ? 0 : ((dj == 2) ? 63 : 99);
                const int base = fl + (di << 6) + dj - 65 + GOF;
                #pragma unroll
                for (int j = 0; j < 9; ++j) wv[j] = sKQg[base + j];
                #pragma unroll
                for (int j = 0; j < 9; ++j) {
                    int c = (fl + j) & 63;
                    wv[j] = (c == cbad) ? 0u : wv[j];
                }
            } else {                               // straddle: generic decode
                #pragma unroll
                for (int j = 0; j < 9; ++j) {
                    int fj = f + j;
                    int tj = fj >> 12, lj = fj & 4095;
                    int dij = (tj * 86) >> 8, djj = tj - 3 * dij;
                    int idx = lj + (dij << 6) + djj - 65 + GOF;
                    unsigned wr = sKQg[idx];
                    int c = lj & 63;
                    int cb = (djj == 0) ? 0 : ((djj == 2) ? 63 : 99);
                    wv[j] = (c == cb) ? 0u : wr;
                }
            }
            const unsigned cw = wv[4];
            const float kc = bflo(cw), qc = bfhi(cw);
            float e0 = __expf(bflo(wv[0]) * qc + kc * bfhi(wv[0]));
            float e1 = __expf(bflo(wv[1]) * qc + kc * bfhi(wv[1]));
            float e2 = __expf(bflo(wv[2]) * qc + kc * bfhi(wv[2]));
            float e3 = __expf(bflo(wv[3]) * qc + kc * bfhi(wv[3]));
            float e4 = __expf(bflo(wv[4]) * qc + kc * bfhi(wv[4]));
            float e5 = __expf(bflo(wv[5]) * qc + kc * bfhi(wv[5]));
            float e6 = __expf(bflo(wv[6]) * qc + kc * bfhi(wv[6]));
            float e7 = __expf(bflo(wv[7]) * qc + kc * bfhi(wv[7]));
            float e8 = __expf(bflo(wv[8]) * qc + kc * bfhi(wv[8]));
            float s = (((e0 + e1) + (e2 + e3)) + ((e4 + e5) + (e6 + e7))) + e8;
            uint2 ci;
            ci.x = cw;
            ci.y = __builtin_bit_cast(unsigned, -__logf(s));
            sCI[r * 512 + tid] = ci;
        }
    }
    __syncthreads();

    // ---- Phase 2: per-output accumulate; outputs l = r*512 + tid ------
    {
        const int c0 = tid & 63;
        float acc[8];
        #pragma unroll
        for (int r = 0; r < 8; ++r) acc[r] = 0.f;

        #pragma unroll
        for (int t = 0; t < 9; ++t) {
            const int di = t / 3, dj = t % 3;
            const int base = tid + (di << 6) + dj - 65 + GOF;
            const bool colbad = (dj == 0) ? (c0 == 0) : ((dj == 2) ? (c0 == 63) : false);
            const int ft = (t << 12) + tid;
            #pragma unroll
            for (int r = 0; r < 8; ++r) {
                const int f = ft + 512 * r;
                const unsigned lp = (unsigned)f / 9u;
                uint2 ci = sCI[lp];
                const float kc = bflo(ci.x), qc = bfhi(ci.x);
                const float cn = __builtin_bit_cast(float, ci.y);
                unsigned wv = sKQg[base + 512 * r];
                float xj = bfu(sXg[base + 512 * r]);
                xj = colbad ? 0.f : xj;
                float e = __expf(fmaf(bflo(wv), qc, fmaf(kc, bfhi(wv), cn)));
                acc[r] = fmaf(e, xj, acc[r]);
            }
        }
        #pragma unroll
        for (int r = 0; r < 8; ++r)
            pre[off + r * 512 + tid] = f2bf(acc[r]);
    }
}

// ---------------------------------------------------------------------------
// Final BN apply + ReLU: bf16 in, f32 out (unchanged)
// ---------------------------------------------------------------------------
__global__ __launch_bounds__(256) void bn_apply_k(
    const ushort_t* __restrict__ yf,
    const float* __restrict__ scale, const float* __restrict__ shift,
    float* __restrict__ out)
{
    const int i = blockIdx.x * 256 + threadIdx.x;   // uint4 index (8 elems)
    const int ch = (i >> 9) & 255;
    const float sc = scale[ch], sh = shift[ch];

    uint4 v = ((const uint4*)yf)[i];
    unsigned w[4] = {v.x, v.y, v.z, v.w};
    float4 o0, o1;
    o0.x = fmaxf(fmaf(bflo(w[0]), sc, sh), 0.f);
    o0.y = fmaxf(fmaf(bfhi(w[0]), sc, sh), 0.f);
    o0.z = fmaxf(fmaf(bflo(w[1]), sc, sh), 0.f);
    o0.w = fmaxf(fmaf(bfhi(w[1]), sc, sh), 0.f);
    o1.x = fmaxf(fmaf(bflo(w[2]), sc, sh), 0.f);
    o1.y = fmaxf(fmaf(bfhi(w[2]), sc, sh), 0.f);
    o1.z = fmaxf(fmaf(bflo(w[3]), sc, sh), 0.f);
    o1.w = fmaxf(fmaf(bfhi(w[3]), sc, sh), 0.f);
    ((float4*)out)[2 * i]     = o0;
    ((float4*)out)[2 * i + 1] = o1;
}

// ---------------------------------------------------------------------------
extern "C" void kernel_launch(void* const* d_in, const int* in_sizes, int n_in,
                              void* d_out, int out_size, void* d_ws, size_t ws_size,
                              hipStream_t stream) {
    const float* x   = (const float*)d_in[0];
    const float* w1  = (const float*)d_in[1];
    const float* b1  = (const float*)d_in[2];
    const float* g1  = (const float*)d_in[3];
    const float* be1 = (const float*)d_in[4];
    const float* w2  = (const float*)d_in[5];
    const float* b2  = (const float*)d_in[6];
    const float* g2  = (const float*)d_in[7];
    const float* be2 = (const float*)d_in[8];
    const float* wf  = (const float*)d_in[9];
    const float* bf  = (const float*)d_in[10];
    const float* gf  = (const float*)d_in[11];
    const float* bef = (const float*)d_in[12];
    float* out = (float*)d_out;

    const size_t NEL = (size_t)NB * CCH * L;       // 4194304
    ushort_t* y1b = (ushort_t*)d_ws;               // conv1 out (bf16); later yf
    ushort_t* y2b = y1b + NEL;                     // conv2 out (bf16); later pre
    float* st = (float*)(y2b + NEL);               // stats: 6 x 256
    float* s1sc = st,        *s1sh = st + 256;
    float* s2sc = st + 512,  *s2sh = st + 768;
    float* sfsc = st + 1024, *sfsh = st + 1280;
    ushort_t* wb1 = (ushort_t*)(st + 1536);        // bf16 weights: 3 x 64K
    ushort_t* wb2 = wb1 + CCH * CCH;
    ushort_t* wbf = wb2 + CCH * CCH;

    wcvt_k<<<192, 256, 0, stream>>>(w1, w2, wf, wb1, wb2, wbf);
    dim3 gg(64, 2, 4);
    dual_gemm_k<<<gg, 256, 0, stream>>>(x, wb1, b1, wb2, b2, y1b, y2b);
    bn_stats2_k<<<512, 256, 0, stream>>>(y1b, g1, be1, s1sc, s1sh,
                                         y2b, g2, be2, s2sc, s2sh);
    attention_k<<<NB * CCH, 512, 0, stream>>>(x, y1b, y2b,
                                              s1sc, s1sh, s2sc, s2sh,
                                              /*pre=*/y2b);
    single_gemm_k<<<gg, 256, 0, stream>>>(/*pre=*/y2b, wbf, bf, /*yf=*/y1b);
    bn_stats_k<<<256, 256, 0, stream>>>(y1b, gf, bef, sfsc, sfsh);
    bn_apply_k<<<(int)(NEL / 2048), 256, 0, stream>>>(y1b, sfsc, sfsh, out);
}

// Round 12
// 161.834 us; speedup vs baseline: 1.3681x; 1.0006x over previous
//
#include <hip/hip_runtime.h>
#include <hip/hip_bf16.h>

#define L 4096
#define CCH 256
#define NB 4
#define KP 40   // padded LDS row length (32 k + 8 pad) in bf16 elems; 80 B rows
#define GOF 72  // guarded-image front offset (alignment-friendly, >= 65)

typedef __attribute__((ext_vector_type(8))) short short8;
typedef __attribute__((ext_vector_type(4))) float f32x4;
typedef unsigned short ushort_t;

__device__ __forceinline__ unsigned short f2bf(float f) {
    unsigned u = __builtin_bit_cast(unsigned, f);
    u += 0x7FFF + ((u >> 16) & 1);
    return (unsigned short)(u >> 16);
}
// packed RNE f32x2 -> bf16x2 (v_cvt_pk_bf16_f32 on gfx950); a in low 16
__device__ __forceinline__ unsigned pk_bf16(float a, float b) {
    __hip_bfloat162 h = __float22bfloat162_rn(make_float2(a, b));
    unsigned u;
    __builtin_memcpy(&u, &h, 4);
    return u;
}
__device__ __forceinline__ float bflo(unsigned w) {
    return __builtin_bit_cast(float, w << 16);
}
__device__ __forceinline__ float bfhi(unsigned w) {
    return __builtin_bit_cast(float, w & 0xFFFF0000u);
}
__device__ __forceinline__ float bfu(ushort_t h) {
    return __builtin_bit_cast(float, (unsigned)h << 16);
}

// ---------------------------------------------------------------------------
// One-time weight conversion: w1|w2|wf (each 256x256 f32) -> bf16
// ---------------------------------------------------------------------------
__global__ __launch_bounds__(256) void wcvt_k(
    const float* __restrict__ w1, const float* __restrict__ w2,
    const float* __restrict__ wf,
    ushort_t* __restrict__ wb1, ushort_t* __restrict__ wb2,
    ushort_t* __restrict__ wbf)
{
    const int mb = blockIdx.x >> 6;          // 0..2: which matrix
    const int i  = (blockIdx.x & 63) * 256 + threadIdx.x;   // float4 index
    const float* src = (mb == 0) ? w1 : (mb == 1) ? w2 : wf;
    ushort_t*    dst = (mb == 0) ? wb1 : (mb == 1) ? wb2 : wbf;
    float4 v = ((const float4*)src)[i];
    uint2 p;
    p.x = pk_bf16(v.x, v.y);
    p.y = pk_bf16(v.z, v.w);
    ((uint2*)dst)[i] = p;
}

// ---------------------------------------------------------------------------
// Dual conv1x1 via bf16 MFMA; bf16 weights (copy staging), packed-cvt x
// staging, bf16 outputs.
// ---------------------------------------------------------------------------
__global__ __launch_bounds__(256, 2) void dual_gemm_k(
    const float* __restrict__ x,
    const ushort_t* __restrict__ wb1, const float* __restrict__ b1,
    const ushort_t* __restrict__ wb2, const float* __restrict__ b2,
    ushort_t* __restrict__ y1, ushort_t* __restrict__ y2)
{
    __shared__ short sA1[128 * KP];
    __shared__ short sA2[128 * KP];
    __shared__ short sB [64 * KP];

    const int tid = threadIdx.x;
    const int l0 = blockIdx.x * 64;
    const int o0 = blockIdx.y * 128;
    const int b  = blockIdx.z;

    const int wv = tid >> 6;
    const int lane = tid & 63;
    const int m = lane & 15;
    const int quad = lane >> 4;

    const float* xb = x + (size_t)b * CCH * L;

    const int sl = tid & 63, soct = tid >> 6;
    const int sr = tid & 127, sh = tid >> 7;

    f32x4 acc1[2][4], acc2[2][4];
    #pragma unroll
    for (int io = 0; io < 2; ++io)
        #pragma unroll
        for (int jl = 0; jl < 4; ++jl) {
            acc1[io][jl] = (f32x4){0.f,0.f,0.f,0.f};
            acc2[io][jl] = (f32x4){0.f,0.f,0.f,0.f};
        }

    for (int s = 0; s < 8; ++s) {
        const int k0 = s * 32;
        __syncthreads();
        {
            const float* xs = xb + (size_t)(k0 + soct * 8) * L + l0 + sl;
            float f[8];
            #pragma unroll
            for (int j = 0; j < 8; ++j) f[j] = xs[(size_t)j * L];
            uint4 v;
            v.x = pk_bf16(f[0], f[1]);
            v.y = pk_bf16(f[2], f[3]);
            v.z = pk_bf16(f[4], f[5]);
            v.w = pk_bf16(f[6], f[7]);
            *(uint4*)&sB[sl * KP + soct * 8] = v;
        }
        {
            const uint4* wp = (const uint4*)&wb1[(size_t)(o0 + sr) * CCH + k0 + sh * 16];
            uint4 p0 = wp[0], p1 = wp[1];
            *(uint4*)&sA1[sr * KP + sh * 16]     = p0;
            *(uint4*)&sA1[sr * KP + sh * 16 + 8] = p1;
            const uint4* wq = (const uint4*)&wb2[(size_t)(o0 + sr) * CCH + k0 + sh * 16];
            uint4 q0 = wq[0], q1 = wq[1];
            *(uint4*)&sA2[sr * KP + sh * 16]     = q0;
            *(uint4*)&sA2[sr * KP + sh * 16 + 8] = q1;
        }
        __syncthreads();
        short8 a1[2], a2[2], bf[4];
        #pragma unroll
        for (int io = 0; io < 2; ++io) {
            a1[io] = *(const short8*)&sA1[(wv * 32 + io * 16 + m) * KP + quad * 8];
            a2[io] = *(const short8*)&sA2[(wv * 32 + io * 16 + m) * KP + quad * 8];
        }
        #pragma unroll
        for (int jl = 0; jl < 4; ++jl)
            bf[jl] = *(const short8*)&sB[(jl * 16 + m) * KP + quad * 8];
        #pragma unroll
        for (int io = 0; io < 2; ++io)
            #pragma unroll
            for (int jl = 0; jl < 4; ++jl) {
                acc1[io][jl] = __builtin_amdgcn_mfma_f32_16x16x32_bf16(a1[io], bf[jl], acc1[io][jl], 0, 0, 0);
                acc2[io][jl] = __builtin_amdgcn_mfma_f32_16x16x32_bf16(a2[io], bf[jl], acc2[io][jl], 0, 0, 0);
            }
    }

    #pragma unroll
    for (int io = 0; io < 2; ++io)
        #pragma unroll
        for (int reg = 0; reg < 4; ++reg) {
            const int o = o0 + wv * 32 + io * 16 + quad * 4 + reg;
            const float bb1 = b1[o], bb2 = b2[o];
            const size_t ro = ((size_t)b * CCH + o) * L + l0 + m;
            unsigned u1a = pk_bf16(acc1[io][0][reg] + bb1, acc1[io][1][reg] + bb1);
            unsigned u1b = pk_bf16(acc1[io][2][reg] + bb1, acc1[io][3][reg] + bb1);
            unsigned u2a = pk_bf16(acc2[io][0][reg] + bb2, acc2[io][1][reg] + bb2);
            unsigned u2b = pk_bf16(acc2[io][2][reg] + bb2, acc2[io][3][reg] + bb2);
            y1[ro]      = (ushort_t)u1a;
            y1[ro + 16] = (ushort_t)(u1a >> 16);
            y1[ro + 32] = (ushort_t)u1b;
            y1[ro + 48] = (ushort_t)(u1b >> 16);
            y2[ro]      = (ushort_t)u2a;
            y2[ro + 16] = (ushort_t)(u2a >> 16);
            y2[ro + 32] = (ushort_t)u2b;
            y2[ro + 48] = (ushort_t)(u2b >> 16);
        }
}

// ---------------------------------------------------------------------------
// Single conv1x1 via bf16 MFMA: bf16 input (pre), bf16 weights, bf16 output
// ---------------------------------------------------------------------------
__global__ __launch_bounds__(256, 2) void single_gemm_k(
    const ushort_t* __restrict__ x,
    const ushort_t* __restrict__ wb, const float* __restrict__ bb,
    ushort_t* __restrict__ y)
{
    __shared__ short sA[128 * KP];
    __shared__ short sB[64 * KP];

    const int tid = threadIdx.x;
    const int l0 = blockIdx.x * 64;
    const int o0 = blockIdx.y * 128;
    const int b  = blockIdx.z;

    const int wv = tid >> 6;
    const int lane = tid & 63;
    const int m = lane & 15;
    const int quad = lane >> 4;

    const ushort_t* xb = x + (size_t)b * CCH * L;

    const int sl = tid & 63, soct = tid >> 6;
    const int sr = tid & 127, sh = tid >> 7;

    f32x4 acc[2][4];
    #pragma unroll
    for (int io = 0; io < 2; ++io)
        #pragma unroll
        for (int jl = 0; jl < 4; ++jl)
            acc[io][jl] = (f32x4){0.f,0.f,0.f,0.f};

    for (int s = 0; s < 8; ++s) {
        const int k0 = s * 32;
        __syncthreads();
        {
            const ushort_t* xs = xb + (size_t)(k0 + soct * 8) * L + l0 + sl;
            short8 v;
            #pragma unroll
            for (int j = 0; j < 8; ++j) v[j] = (short)xs[(size_t)j * L];
            *(short8*)&sB[sl * KP + soct * 8] = v;
        }
        {
            const uint4* wp = (const uint4*)&wb[(size_t)(o0 + sr) * CCH + k0 + sh * 16];
            uint4 p0 = wp[0], p1 = wp[1];
            *(uint4*)&sA[sr * KP + sh * 16]     = p0;
            *(uint4*)&sA[sr * KP + sh * 16 + 8] = p1;
        }
        __syncthreads();
        short8 a[2], bf[4];
        #pragma unroll
        for (int io = 0; io < 2; ++io)
            a[io] = *(const short8*)&sA[(wv * 32 + io * 16 + m) * KP + quad * 8];
        #pragma unroll
        for (int jl = 0; jl < 4; ++jl)
            bf[jl] = *(const short8*)&sB[(jl * 16 + m) * KP + quad * 8];
        #pragma unroll
        for (int io = 0; io < 2; ++io)
            #pragma unroll
            for (int jl = 0; jl < 4; ++jl)
                acc[io][jl] = __builtin_amdgcn_mfma_f32_16x16x32_bf16(a[io], bf[jl], acc[io][jl], 0, 0, 0);
    }

    #pragma unroll
    for (int io = 0; io < 2; ++io)
        #pragma unroll
        for (int reg = 0; reg < 4; ++reg) {
            const int o = o0 + wv * 32 + io * 16 + quad * 4 + reg;
            const float b0 = bb[o];
            const size_t ro = ((size_t)b * CCH + o) * L + l0 + m;
            unsigned ua = pk_bf16(acc[io][0][reg] + b0, acc[io][1][reg] + b0);
            unsigned ub = pk_bf16(acc[io][2][reg] + b0, acc[io][3][reg] + b0);
            y[ro]      = (ushort_t)ua;
            y[ro + 16] = (ushort_t)(ua >> 16);
            y[ro + 32] = (ushort_t)ub;
            y[ro + 48] = (ushort_t)(ub >> 16);
        }
}

// ---------------------------------------------------------------------------
// BatchNorm stats over bf16 tensor -> finalized scale/shift (unchanged)
// ---------------------------------------------------------------------------
__device__ __forceinline__ void bn_stats_body(
    const ushort_t* y, const float* gamma, const float* beta,
    float* scale, float* shift, int c, int tid)
{
    float s = 0.f, s2 = 0.f;
    for (int b = 0; b < NB; ++b) {
        const uint4* p = (const uint4*)(y + ((size_t)b * CCH + c) * L);
        #pragma unroll
        for (int r = 0; r < 2; ++r) {
            uint4 v = p[r * 256 + tid];
            unsigned w[4] = {v.x, v.y, v.z, v.w};
            #pragma unroll
            for (int u = 0; u < 4; ++u) {
                float a = bflo(w[u]), bb = bfhi(w[u]);
                s  += a + bb;
                s2 += a * a + bb * bb;
            }
        }
    }
    #pragma unroll
    for (int off = 32; off > 0; off >>= 1) {
        s  += __shfl_down(s, off);
        s2 += __shfl_down(s2, off);
    }
    __shared__ float red[2][4];
    if ((tid & 63) == 0) { red[0][tid >> 6] = s; red[1][tid >> 6] = s2; }
    __syncthreads();
    if (tid == 0) {
        float S  = red[0][0] + red[0][1] + red[0][2] + red[0][3];
        float S2 = red[1][0] + red[1][1] + red[1][2] + red[1][3];
        const float invN = 1.f / (NB * (float)L);
        float mean = S * invN;
        float var  = S2 * invN - mean * mean;
        float rstd = rsqrtf(var + 1e-5f);
        float g = gamma[c];
        scale[c] = g * rstd;
        shift[c] = beta[c] - mean * g * rstd;
    }
}

__global__ __launch_bounds__(256) void bn_stats_k(
    const ushort_t* __restrict__ y, const float* __restrict__ gamma,
    const float* __restrict__ beta,
    float* __restrict__ scale, float* __restrict__ shift)
{
    bn_stats_body(y, gamma, beta, scale, shift, blockIdx.x, threadIdx.x);
}

__global__ __launch_bounds__(256) void bn_stats2_k(
    const ushort_t* __restrict__ y1, const float* __restrict__ g1, const float* __restrict__ be1,
    float* __restrict__ sc1, float* __restrict__ sh1,
    const ushort_t* __restrict__ y2, const float* __restrict__ g2, const float* __restrict__ be2,
    float* __restrict__ sc2, float* __restrict__ sh2)
{
    const int c = blockIdx.x & 255;
    if (blockIdx.x < 256) bn_stats_body(y1, g1, be1, sc1, sh1, c, threadIdx.x);
    else                  bn_stats_body(y2, g2, be2, sc2, sh2, c, threadIdx.x);
}

// ---------------------------------------------------------------------------
// Attention v3 (R9 structure) with packed-cvt staging.
// ---------------------------------------------------------------------------
__global__ __launch_bounds__(512, 4) void attention_k(
    const float* __restrict__ x,
    const ushort_t* __restrict__ y1,
    const ushort_t* __restrict__ y2,
    const float* __restrict__ s1sc, const float* __restrict__ s1sh,
    const float* __restrict__ s2sc, const float* __restrict__ s2sh,
    ushort_t* __restrict__ pre)
{
    __shared__ unsigned sKQg[4240];   // [GOF+s] = packed bf16 (k,q); guards zero
    __shared__ ushort_t sXg [4240];   // [GOF+s] = bf16 x; guards zero
    __shared__ uint2    sCI [L];      // {packed (kc,qc), bits(-ln S)} per window

    const int bc = blockIdx.x;
    const int tid = threadIdx.x;
    const int ch = bc & 255;
    const size_t off = (size_t)bc * L;

    const float sc1 = s1sc[ch], sh1 = s1sh[ch];
    const float sc2 = s2sc[ch], sh2 = s2sh[ch];

    // ---- stage + guards ----------------------------------------------
    if (tid < GOF)  { sKQg[tid] = 0; sXg[tid] = 0; }
    if (tid < 72)   { sKQg[GOF + 4096 + tid] = 0; sXg[GOF + 4096 + tid] = 0; }
    {
        uint4 ak = ((const uint4*)(y1 + off))[tid];
        uint4 aq = ((const uint4*)(y2 + off))[tid];
        float4 xa = ((const float4*)(x + off))[2 * tid];
        float4 xb = ((const float4*)(x + off))[2 * tid + 1];
        unsigned wk[4] = {ak.x, ak.y, ak.z, ak.w};
        unsigned wq[4] = {aq.x, aq.y, aq.z, aq.w};
        unsigned kq[8];
        #pragma unroll
        for (int u = 0; u < 4; ++u) {
            float klo = fmaxf(fmaf(bflo(wk[u]), sc1, sh1), 0.f);
            float khi = fmaxf(fmaf(bfhi(wk[u]), sc1, sh1), 0.f);
            float qlo = fmaxf(fmaf(bflo(wq[u]), sc2, sh2), 0.f);
            float qhi = fmaxf(fmaf(bfhi(wq[u]), sc2, sh2), 0.f);
            kq[2*u]   = pk_bf16(klo, qlo);
            kq[2*u+1] = pk_bf16(khi, qhi);
        }
        *(uint4*)&sKQg[GOF + 8 * tid]     = make_uint4(kq[0], kq[1], kq[2], kq[3]);
        *(uint4*)&sKQg[GOF + 8 * tid + 4] = make_uint4(kq[4], kq[5], kq[6], kq[7]);
        uint4 xp;
        xp.x = pk_bf16(xa.x, xa.y);
        xp.y = pk_bf16(xa.z, xa.w);
        xp.z = pk_bf16(xb.x, xb.y);
        xp.w = pk_bf16(xb.z, xb.w);
        *(uint4*)&sXg[GOF + 8 * tid] = xp;
    }
    __syncthreads();

    // ---- Phase 1: per-window center + -ln(denominator) ----------------
    {
        const int fbase = 9 * tid;
        #pragma unroll
        for (int r = 0; r < 8; ++r) {
            const int f  = fbase + 4608 * r;
            const int t  = f >> 12;
            const int fl = f & 4095;
            unsigned wv[9];
            if (fl < 4088) {                       // fast path: single tap t
                const int di = (t * 86) >> 8;
                const int dj = t - 3 * di;
                const int cbad = (dj == 0) ? 0 : ((dj == 2) ? 63 : 99);
                const int base = fl + (di << 6) + dj - 65 + GOF;
                #pragma unroll
                for (int j = 0; j < 9; ++j) wv[j] = sKQg[base + j];
                #pragma unroll
                for (int j = 0; j < 9; ++j) {
                    int c = (fl + j) & 63;
                    wv[j] = (c == cbad) ? 0u : wv[j];
                }
            } else {                               // straddle: generic decode
                #pragma unroll
                for (int j = 0; j < 9; ++j) {
                    int fj = f + j;
                    int tj = fj >> 12, lj = fj & 4095;
                    int dij = (tj * 86) >> 8, djj = tj - 3 * dij;
                    int idx = lj + (dij << 6) + djj - 65 + GOF;
                    unsigned wr = sKQg[idx];
                    int c = lj & 63;
                    int cb = (djj == 0) ? 0 : ((djj == 2) ? 63 : 99);
                    wv[j] = (c == cb) ? 0u : wr;
                }
            }
            const unsigned cw = wv[4];
            const float kc = bflo(cw), qc = bfhi(cw);
            float e0 = __expf(bflo(wv[0]) * qc + kc * bfhi(wv[0]));
            float e1 = __expf(bflo(wv[1]) * qc + kc * bfhi(wv[1]));
            float e2 = __expf(bflo(wv[2]) * qc + kc * bfhi(wv[2]));
            float e3 = __expf(bflo(wv[3]) * qc + kc * bfhi(wv[3]));
            float e4 = __expf(bflo(wv[4]) * qc + kc * bfhi(wv[4]));
            float e5 = __expf(bflo(wv[5]) * qc + kc * bfhi(wv[5]));
            float e6 = __expf(bflo(wv[6]) * qc + kc * bfhi(wv[6]));
            float e7 = __expf(bflo(wv[7]) * qc + kc * bfhi(wv[7]));
            float e8 = __expf(bflo(wv[8]) * qc + kc * bfhi(wv[8]));
            float s = (((e0 + e1) + (e2 + e3)) + ((e4 + e5) + (e6 + e7))) + e8;
            uint2 ci;
            ci.x = cw;
            ci.y = __builtin_bit_cast(unsigned, -__logf(s));
            sCI[r * 512 + tid] = ci;
        }
    }
    __syncthreads();

    // ---- Phase 2: per-output accumulate; outputs l = r*512 + tid ------
    {
        const int c0 = tid & 63;
        float acc[8];
        #pragma unroll
        for (int r = 0; r < 8; ++r) acc[r] = 0.f;

        #pragma unroll
        for (int t = 0; t < 9; ++t) {
            const int di = t / 3, dj = t % 3;
            const int base = tid + (di << 6) + dj - 65 + GOF;
            const bool colbad = (dj == 0) ? (c0 == 0) : ((dj == 2) ? (c0 == 63) : false);
            const int ft = (t << 12) + tid;
            #pragma unroll
            for (int r = 0; r < 8; ++r) {
                const int f = ft + 512 * r;
                const unsigned lp = (unsigned)f / 9u;
                uint2 ci = sCI[lp];
                const float kc = bflo(ci.x), qc = bfhi(ci.x);
                const float cn = __builtin_bit_cast(float, ci.y);
                unsigned wv = sKQg[base + 512 * r];
                float xj = bfu(sXg[base + 512 * r]);
                xj = colbad ? 0.f : xj;
                float e = __expf(fmaf(bflo(wv), qc, fmaf(kc, bfhi(wv), cn)));
                acc[r] = fmaf(e, xj, acc[r]);
            }
        }
        #pragma unroll
        for (int r = 0; r < 8; ++r)
            pre[off + r * 512 + tid] = f2bf(acc[r]);
    }
}

// ---------------------------------------------------------------------------
// Final BN apply + ReLU: bf16 in, f32 out (unchanged)
// ---------------------------------------------------------------------------
__global__ __launch_bounds__(256) void bn_apply_k(
    const ushort_t* __restrict__ yf,
    const float* __restrict__ scale, const float* __restrict__ shift,
    float* __restrict__ out)
{
    const int i = blockIdx.x * 256 + threadIdx.x;   // uint4 index (8 elems)
    const int ch = (i >> 9) & 255;
    const float sc = scale[ch], sh = shift[ch];

    uint4 v = ((const uint4*)yf)[i];
    unsigned w[4] = {v.x, v.y, v.z, v.w};
    float4 o0, o1;
    o0.x = fmaxf(fmaf(bflo(w[0]), sc, sh), 0.f);
    o0.y = fmaxf(fmaf(bfhi(w[0]), sc, sh), 0.f);
    o0.z = fmaxf(fmaf(bflo(w[1]), sc, sh), 0.f);
    o0.w = fmaxf(fmaf(bfhi(w[1]), sc, sh), 0.f);
    o1.x = fmaxf(fmaf(bflo(w[2]), sc, sh), 0.f);
    o1.y = fmaxf(fmaf(bfhi(w[2]), sc, sh), 0.f);
    o1.z = fmaxf(fmaf(bflo(w[3]), sc, sh), 0.f);
    o1.w = fmaxf(fmaf(bfhi(w[3]), sc, sh), 0.f);
    ((float4*)out)[2 * i]     = o0;
    ((float4*)out)[2 * i + 1] = o1;
}

// ---------------------------------------------------------------------------
extern "C" void kernel_launch(void* const* d_in, const int* in_sizes, int n_in,
                              void* d_out, int out_size, void* d_ws, size_t ws_size,
                              hipStream_t stream) {
    const float* x   = (const float*)d_in[0];
    const float* w1  = (const float*)d_in[1];
    const float* b1  = (const float*)d_in[2];
    const float* g1  = (const float*)d_in[3];
    const float* be1 = (const float*)d_in[4];
    const float* w2  = (const float*)d_in[5];
    const float* b2  = (const float*)d_in[6];
    const float* g2  = (const float*)d_in[7];
    const float* be2 = (const float*)d_in[8];
    const float* wf  = (const float*)d_in[9];
    const float* bf  = (const float*)d_in[10];
    const float* gf  = (const float*)d_in[11];
    const float* bef = (const float*)d_in[12];
    float* out = (float*)d_out;

    const size_t NEL = (size_t)NB * CCH * L;       // 4194304
    ushort_t* y1b = (ushort_t*)d_ws;               // conv1 out (bf16); later yf
    ushort_t* y2b = y1b + NEL;                     // conv2 out (bf16); later pre
    float* st = (float*)(y2b + NEL);               // stats: 6 x 256
    float* s1sc = st,        *s1sh = st + 256;
    float* s2sc = st + 512,  *s2sh = st + 768;
    float* sfsc = st + 1024, *sfsh = st + 1280;
    ushort_t* wb1 = (ushort_t*)(st + 1536);        // bf16 weights: 3 x 64K
    ushort_t* wb2 = wb1 + CCH * CCH;
    ushort_t* wbf = wb2 + CCH * CCH;

    wcvt_k<<<192, 256, 0, stream>>>(w1, w2, wf, wb1, wb2, wbf);
    dim3 gg(64, 2, 4);
    dual_gemm_k<<<gg, 256, 0, stream>>>(x, wb1, b1, wb2, b2, y1b, y2b);
    bn_stats2_k<<<512, 256, 0, stream>>>(y1b, g1, be1, s1sc, s1sh,
                                         y2b, g2, be2, s2sc, s2sh);
    attention_k<<<NB * CCH, 512, 0, stream>>>(x, y1b, y2b,
                                              s1sc, s1sh, s2sc, s2sh,
                                              /*pre=*/y2b);
    single_gemm_k<<<gg, 256, 0, stream>>>(/*pre=*/y2b, wbf, bf, /*yf=*/y1b);
    bn_stats_k<<<256, 256, 0, stream>>>(y1b, gf, bef, sfsc, sfsh);
    bn_apply_k<<<(int)(NEL / 2048), 256, 0, stream>>>(y1b, sfsc, sfsh, out);
}

// Round 13
// 160.484 us; speedup vs baseline: 1.3796x; 1.0084x over previous
//
#include <hip/hip_runtime.h>
#include <hip/hip_bf16.h>

#define L 4096
#define CCH 256
#define NB 4
#define KP 40   // padded LDS row length (32 k + 8 pad) in bf16 elems; 80 B rows
#define GOF 72  // guarded-image front offset (alignment-friendly, >= 65)

typedef __attribute__((ext_vector_type(8))) short short8;
typedef __attribute__((ext_vector_type(4))) float f32x4;
typedef unsigned short ushort_t;

__device__ __forceinline__ unsigned short f2bf(float f) {
    unsigned u = __builtin_bit_cast(unsigned, f);
    u += 0x7FFF + ((u >> 16) & 1);
    return (unsigned short)(u >> 16);
}
// packed RNE f32x2 -> bf16x2; used in GEMM epilogues / staging (helped there)
__device__ __forceinline__ unsigned pk_bf16(float a, float b) {
    __hip_bfloat162 h = __float22bfloat162_rn(make_float2(a, b));
    unsigned u;
    __builtin_memcpy(&u, &h, 4);
    return u;
}
__device__ __forceinline__ float bflo(unsigned w) {
    return __builtin_bit_cast(float, w << 16);
}
__device__ __forceinline__ float bfhi(unsigned w) {
    return __builtin_bit_cast(float, w & 0xFFFF0000u);
}
__device__ __forceinline__ float bfu(ushort_t h) {
    return __builtin_bit_cast(float, (unsigned)h << 16);
}

// ---------------------------------------------------------------------------
// One-time weight conversion: w1|w2|wf (each 256x256 f32) -> bf16
// ---------------------------------------------------------------------------
__global__ __launch_bounds__(256) void wcvt_k(
    const float* __restrict__ w1, const float* __restrict__ w2,
    const float* __restrict__ wf,
    ushort_t* __restrict__ wb1, ushort_t* __restrict__ wb2,
    ushort_t* __restrict__ wbf)
{
    const int mb = blockIdx.x >> 6;          // 0..2: which matrix
    const int i  = (blockIdx.x & 63) * 256 + threadIdx.x;   // float4 index
    const float* src = (mb == 0) ? w1 : (mb == 1) ? w2 : wf;
    ushort_t*    dst = (mb == 0) ? wb1 : (mb == 1) ? wb2 : wbf;
    float4 v = ((const float4*)src)[i];
    uint2 p;
    p.x = pk_bf16(v.x, v.y);
    p.y = pk_bf16(v.z, v.w);
    ((uint2*)dst)[i] = p;
}

// ---------------------------------------------------------------------------
// Dual conv1x1 via bf16 MFMA; bf16 weights (copy staging), packed-cvt x
// staging, bf16 outputs.
// ---------------------------------------------------------------------------
__global__ __launch_bounds__(256, 2) void dual_gemm_k(
    const float* __restrict__ x,
    const ushort_t* __restrict__ wb1, const float* __restrict__ b1,
    const ushort_t* __restrict__ wb2, const float* __restrict__ b2,
    ushort_t* __restrict__ y1, ushort_t* __restrict__ y2)
{
    __shared__ short sA1[128 * KP];
    __shared__ short sA2[128 * KP];
    __shared__ short sB [64 * KP];

    const int tid = threadIdx.x;
    const int l0 = blockIdx.x * 64;
    const int o0 = blockIdx.y * 128;
    const int b  = blockIdx.z;

    const int wv = tid >> 6;
    const int lane = tid & 63;
    const int m = lane & 15;
    const int quad = lane >> 4;

    const float* xb = x + (size_t)b * CCH * L;

    const int sl = tid & 63, soct = tid >> 6;
    const int sr = tid & 127, sh = tid >> 7;

    f32x4 acc1[2][4], acc2[2][4];
    #pragma unroll
    for (int io = 0; io < 2; ++io)
        #pragma unroll
        for (int jl = 0; jl < 4; ++jl) {
            acc1[io][jl] = (f32x4){0.f,0.f,0.f,0.f};
            acc2[io][jl] = (f32x4){0.f,0.f,0.f,0.f};
        }

    for (int s = 0; s < 8; ++s) {
        const int k0 = s * 32;
        __syncthreads();
        {
            const float* xs = xb + (size_t)(k0 + soct * 8) * L + l0 + sl;
            float f[8];
            #pragma unroll
            for (int j = 0; j < 8; ++j) f[j] = xs[(size_t)j * L];
            uint4 v;
            v.x = pk_bf16(f[0], f[1]);
            v.y = pk_bf16(f[2], f[3]);
            v.z = pk_bf16(f[4], f[5]);
            v.w = pk_bf16(f[6], f[7]);
            *(uint4*)&sB[sl * KP + soct * 8] = v;
        }
        {
            const uint4* wp = (const uint4*)&wb1[(size_t)(o0 + sr) * CCH + k0 + sh * 16];
            uint4 p0 = wp[0], p1 = wp[1];
            *(uint4*)&sA1[sr * KP + sh * 16]     = p0;
            *(uint4*)&sA1[sr * KP + sh * 16 + 8] = p1;
            const uint4* wq = (const uint4*)&wb2[(size_t)(o0 + sr) * CCH + k0 + sh * 16];
            uint4 q0 = wq[0], q1 = wq[1];
            *(uint4*)&sA2[sr * KP + sh * 16]     = q0;
            *(uint4*)&sA2[sr * KP + sh * 16 + 8] = q1;
        }
        __syncthreads();
        short8 a1[2], a2[2], bf[4];
        #pragma unroll
        for (int io = 0; io < 2; ++io) {
            a1[io] = *(const short8*)&sA1[(wv * 32 + io * 16 + m) * KP + quad * 8];
            a2[io] = *(const short8*)&sA2[(wv * 32 + io * 16 + m) * KP + quad * 8];
        }
        #pragma unroll
        for (int jl = 0; jl < 4; ++jl)
            bf[jl] = *(const short8*)&sB[(jl * 16 + m) * KP + quad * 8];
        #pragma unroll
        for (int io = 0; io < 2; ++io)
            #pragma unroll
            for (int jl = 0; jl < 4; ++jl) {
                acc1[io][jl] = __builtin_amdgcn_mfma_f32_16x16x32_bf16(a1[io], bf[jl], acc1[io][jl], 0, 0, 0);
                acc2[io][jl] = __builtin_amdgcn_mfma_f32_16x16x32_bf16(a2[io], bf[jl], acc2[io][jl], 0, 0, 0);
            }
    }

    #pragma unroll
    for (int io = 0; io < 2; ++io)
        #pragma unroll
        for (int reg = 0; reg < 4; ++reg) {
            const int o = o0 + wv * 32 + io * 16 + quad * 4 + reg;
            const float bb1 = b1[o], bb2 = b2[o];
            const size_t ro = ((size_t)b * CCH + o) * L + l0 + m;
            unsigned u1a = pk_bf16(acc1[io][0][reg] + bb1, acc1[io][1][reg] + bb1);
            unsigned u1b = pk_bf16(acc1[io][2][reg] + bb1, acc1[io][3][reg] + bb1);
            unsigned u2a = pk_bf16(acc2[io][0][reg] + bb2, acc2[io][1][reg] + bb2);
            unsigned u2b = pk_bf16(acc2[io][2][reg] + bb2, acc2[io][3][reg] + bb2);
            y1[ro]      = (ushort_t)u1a;
            y1[ro + 16] = (ushort_t)(u1a >> 16);
            y1[ro + 32] = (ushort_t)u1b;
            y1[ro + 48] = (ushort_t)(u1b >> 16);
            y2[ro]      = (ushort_t)u2a;
            y2[ro + 16] = (ushort_t)(u2a >> 16);
            y2[ro + 32] = (ushort_t)u2b;
            y2[ro + 48] = (ushort_t)(u2b >> 16);
        }
}

// ---------------------------------------------------------------------------
// Single conv1x1 via bf16 MFMA: bf16 input (pre), bf16 weights, bf16 output
// ---------------------------------------------------------------------------
__global__ __launch_bounds__(256, 2) void single_gemm_k(
    const ushort_t* __restrict__ x,
    const ushort_t* __restrict__ wb, const float* __restrict__ bb,
    ushort_t* __restrict__ y)
{
    __shared__ short sA[128 * KP];
    __shared__ short sB[64 * KP];

    const int tid = threadIdx.x;
    const int l0 = blockIdx.x * 64;
    const int o0 = blockIdx.y * 128;
    const int b  = blockIdx.z;

    const int wv = tid >> 6;
    const int lane = tid & 63;
    const int m = lane & 15;
    const int quad = lane >> 4;

    const ushort_t* xb = x + (size_t)b * CCH * L;

    const int sl = tid & 63, soct = tid >> 6;
    const int sr = tid & 127, sh = tid >> 7;

    f32x4 acc[2][4];
    #pragma unroll
    for (int io = 0; io < 2; ++io)
        #pragma unroll
        for (int jl = 0; jl < 4; ++jl)
            acc[io][jl] = (f32x4){0.f,0.f,0.f,0.f};

    for (int s = 0; s < 8; ++s) {
        const int k0 = s * 32;
        __syncthreads();
        {
            const ushort_t* xs = xb + (size_t)(k0 + soct * 8) * L + l0 + sl;
            short8 v;
            #pragma unroll
            for (int j = 0; j < 8; ++j) v[j] = (short)xs[(size_t)j * L];
            *(short8*)&sB[sl * KP + soct * 8] = v;
        }
        {
            const uint4* wp = (const uint4*)&wb[(size_t)(o0 + sr) * CCH + k0 + sh * 16];
            uint4 p0 = wp[0], p1 = wp[1];
            *(uint4*)&sA[sr * KP + sh * 16]     = p0;
            *(uint4*)&sA[sr * KP + sh * 16 + 8] = p1;
        }
        __syncthreads();
        short8 a[2], bf[4];
        #pragma unroll
        for (int io = 0; io < 2; ++io)
            a[io] = *(const short8*)&sA[(wv * 32 + io * 16 + m) * KP + quad * 8];
        #pragma unroll
        for (int jl = 0; jl < 4; ++jl)
            bf[jl] = *(const short8*)&sB[(jl * 16 + m) * KP + quad * 8];
        #pragma unroll
        for (int io = 0; io < 2; ++io)
            #pragma unroll
            for (int jl = 0; jl < 4; ++jl)
                acc[io][jl] = __builtin_amdgcn_mfma_f32_16x16x32_bf16(a[io], bf[jl], acc[io][jl], 0, 0, 0);
    }

    #pragma unroll
    for (int io = 0; io < 2; ++io)
        #pragma unroll
        for (int reg = 0; reg < 4; ++reg) {
            const int o = o0 + wv * 32 + io * 16 + quad * 4 + reg;
            const float b0 = bb[o];
            const size_t ro = ((size_t)b * CCH + o) * L + l0 + m;
            unsigned ua = pk_bf16(acc[io][0][reg] + b0, acc[io][1][reg] + b0);
            unsigned ub = pk_bf16(acc[io][2][reg] + b0, acc[io][3][reg] + b0);
            y[ro]      = (ushort_t)ua;
            y[ro + 16] = (ushort_t)(ua >> 16);
            y[ro + 32] = (ushort_t)ub;
            y[ro + 48] = (ushort_t)(ub >> 16);
        }
}

// ---------------------------------------------------------------------------
// BatchNorm stats over bf16 tensor -> finalized scale/shift (unchanged)
// ---------------------------------------------------------------------------
__device__ __forceinline__ void bn_stats_body(
    const ushort_t* y, const float* gamma, const float* beta,
    float* scale, float* shift, int c, int tid)
{
    float s = 0.f, s2 = 0.f;
    for (int b = 0; b < NB; ++b) {
        const uint4* p = (const uint4*)(y + ((size_t)b * CCH + c) * L);
        #pragma unroll
        for (int r = 0; r < 2; ++r) {
            uint4 v = p[r * 256 + tid];
            unsigned w[4] = {v.x, v.y, v.z, v.w};
            #pragma unroll
            for (int u = 0; u < 4; ++u) {
                float a = bflo(w[u]), bb = bfhi(w[u]);
                s  += a + bb;
                s2 += a * a + bb * bb;
            }
        }
    }
    #pragma unroll
    for (int off = 32; off > 0; off >>= 1) {
        s  += __shfl_down(s, off);
        s2 += __shfl_down(s2, off);
    }
    __shared__ float red[2][4];
    if ((tid & 63) == 0) { red[0][tid >> 6] = s; red[1][tid >> 6] = s2; }
    __syncthreads();
    if (tid == 0) {
        float S  = red[0][0] + red[0][1] + red[0][2] + red[0][3];
        float S2 = red[1][0] + red[1][1] + red[1][2] + red[1][3];
        const float invN = 1.f / (NB * (float)L);
        float mean = S * invN;
        float var  = S2 * invN - mean * mean;
        float rstd = rsqrtf(var + 1e-5f);
        float g = gamma[c];
        scale[c] = g * rstd;
        shift[c] = beta[c] - mean * g * rstd;
    }
}

__global__ __launch_bounds__(256) void bn_stats_k(
    const ushort_t* __restrict__ y, const float* __restrict__ gamma,
    const float* __restrict__ beta,
    float* __restrict__ scale, float* __restrict__ shift)
{
    bn_stats_body(y, gamma, beta, scale, shift, blockIdx.x, threadIdx.x);
}

__global__ __launch_bounds__(256) void bn_stats2_k(
    const ushort_t* __restrict__ y1, const float* __restrict__ g1, const float* __restrict__ be1,
    float* __restrict__ sc1, float* __restrict__ sh1,
    const ushort_t* __restrict__ y2, const float* __restrict__ g2, const float* __restrict__ be2,
    float* __restrict__ sc2, float* __restrict__ sh2)
{
    const int c = blockIdx.x & 255;
    if (blockIdx.x < 256) bn_stats_body(y1, g1, be1, sc1, sh1, c, threadIdx.x);
    else                  bn_stats_body(y2, g2, be2, sc2, sh2, c, threadIdx.x);
}

// ---------------------------------------------------------------------------
// Attention v3 (R10 form exactly: f2bf staging — pk_bf16 regressed it in R12).
// ---------------------------------------------------------------------------
__global__ __launch_bounds__(512, 4) void attention_k(
    const float* __restrict__ x,
    const ushort_t* __restrict__ y1,
    const ushort_t* __restrict__ y2,
    const float* __restrict__ s1sc, const float* __restrict__ s1sh,
    const float* __restrict__ s2sc, const float* __restrict__ s2sh,
    ushort_t* __restrict__ pre)
{
    __shared__ unsigned sKQg[4240];   // [GOF+s] = packed bf16 (k,q); guards zero
    __shared__ ushort_t sXg [4240];   // [GOF+s] = bf16 x; guards zero
    __shared__ uint2    sCI [L];      // {packed (kc,qc), bits(-ln S)} per window

    const int bc = blockIdx.x;
    const int tid = threadIdx.x;
    const int ch = bc & 255;
    const size_t off = (size_t)bc * L;

    const float sc1 = s1sc[ch], sh1 = s1sh[ch];
    const float sc2 = s2sc[ch], sh2 = s2sh[ch];

    // ---- stage + guards ----------------------------------------------
    if (tid < GOF)  { sKQg[tid] = 0; sXg[tid] = 0; }
    if (tid < 72)   { sKQg[GOF + 4096 + tid] = 0; sXg[GOF + 4096 + tid] = 0; }
    {
        uint4 ak = ((const uint4*)(y1 + off))[tid];
        uint4 aq = ((const uint4*)(y2 + off))[tid];
        float4 xa = ((const float4*)(x + off))[2 * tid];
        float4 xb = ((const float4*)(x + off))[2 * tid + 1];
        unsigned wk[4] = {ak.x, ak.y, ak.z, ak.w};
        unsigned wq[4] = {aq.x, aq.y, aq.z, aq.w};
        unsigned kq[8];
        #pragma unroll
        for (int u = 0; u < 4; ++u) {
            float klo = fmaxf(fmaf(bflo(wk[u]), sc1, sh1), 0.f);
            float khi = fmaxf(fmaf(bfhi(wk[u]), sc1, sh1), 0.f);
            float qlo = fmaxf(fmaf(bflo(wq[u]), sc2, sh2), 0.f);
            float qhi = fmaxf(fmaf(bfhi(wq[u]), sc2, sh2), 0.f);
            kq[2*u]   = (unsigned)f2bf(klo) | ((unsigned)f2bf(qlo) << 16);
            kq[2*u+1] = (unsigned)f2bf(khi) | ((unsigned)f2bf(qhi) << 16);
        }
        *(uint4*)&sKQg[GOF + 8 * tid]     = make_uint4(kq[0], kq[1], kq[2], kq[3]);
        *(uint4*)&sKQg[GOF + 8 * tid + 4] = make_uint4(kq[4], kq[5], kq[6], kq[7]);
        float xv[8] = {xa.x, xa.y, xa.z, xa.w, xb.x, xb.y, xb.z, xb.w};
        unsigned xp[4];
        #pragma unroll
        for (int u = 0; u < 4; ++u)
            xp[u] = (unsigned)f2bf(xv[2*u]) | ((unsigned)f2bf(xv[2*u+1]) << 16);
        *(uint4*)&sXg[GOF + 8 * tid] = make_uint4(xp[0], xp[1], xp[2], xp[3]);
    }
    __syncthreads();

    // ---- Phase 1: per-window center + -ln(denominator) ----------------
    {
        const int fbase = 9 * tid;
        #pragma unroll
        for (int r = 0; r < 8; ++r) {
            const int f  = fbase + 4608 * r;
            const int t  = f >> 12;
            const int fl = f & 4095;
            unsigned wv[9];
            if (fl < 4088) {                       // fast path: single tap t
                const int di = (t * 86) >> 8;
                const int dj = t - 3 * di;
                const int cbad = (dj == 0) ? 0 : ((dj == 2) ? 63 : 99);
                const int base = fl + (di << 6) + dj - 65 + GOF;
                #pragma unroll
                for (int j = 0; j < 9; ++j) wv[j] = sKQg[base + j];
                #pragma unroll
                for (int j = 0; j < 9; ++j) {
                    int c = (fl + j) & 63;
                    wv[j] = (c == cbad) ? 0u : wv[j];
                }
            } else {                               // straddle: generic decode
                #pragma unroll
                for (int j = 0; j < 9; ++j) {
                    int fj = f + j;
                    int tj = fj >> 12, lj = fj & 4095;
                    int dij = (tj * 86) >> 8, djj = tj - 3 * dij;
                    int idx = lj + (dij << 6) + djj - 65 + GOF;
                    unsigned wr = sKQg[idx];
                    int c = lj & 63;
                    int cb = (djj == 0) ? 0 : ((djj == 2) ? 63 : 99);
                    wv[j] = (c == cb) ? 0u : wr;
                }
            }
            const unsigned cw = wv[4];
            const float kc = bflo(cw), qc = bfhi(cw);
            float e0 = __expf(bflo(wv[0]) * qc + kc * bfhi(wv[0]));
            float e1 = __expf(bflo(wv[1]) * qc + kc * bfhi(wv[1]));
            float e2 = __expf(bflo(wv[2]) * qc + kc * bfhi(wv[2]));
            float e3 = __expf(bflo(wv[3]) * qc + kc * bfhi(wv[3]));
            float e4 = __expf(bflo(wv[4]) * qc + kc * bfhi(wv[4]));
            float e5 = __expf(bflo(wv[5]) * qc + kc * bfhi(wv[5]));
            float e6 = __expf(bflo(wv[6]) * qc + kc * bfhi(wv[6]));
            float e7 = __expf(bflo(wv[7]) * qc + kc * bfhi(wv[7]));
            float e8 = __expf(bflo(wv[8]) * qc + kc * bfhi(wv[8]));
            float s = (((e0 + e1) + (e2 + e3)) + ((e4 + e5) + (e6 + e7))) + e8;
            uint2 ci;
            ci.x = cw;
            ci.y = __builtin_bit_cast(unsigned, -__logf(s));
            sCI[r * 512 + tid] = ci;
        }
    }
    __syncthreads();

    // ---- Phase 2: per-output accumulate; outputs l = r*512 + tid ------
    {
        const int c0 = tid & 63;
        float acc[8];
        #pragma unroll
        for (int r = 0; r < 8; ++r) acc[r] = 0.f;

        #pragma unroll
        for (int t = 0; t < 9; ++t) {
            const int di = t / 3, dj = t % 3;
            const int base = tid + (di << 6) + dj - 65 + GOF;
            const bool colbad = (dj == 0) ? (c0 == 0) : ((dj == 2) ? (c0 == 63) : false);
            const int ft = (t << 12) + tid;
            #pragma unroll
            for (int r = 0; r < 8; ++r) {
                const int f = ft + 512 * r;
                const unsigned lp = (unsigned)f / 9u;
                uint2 ci = sCI[lp];
                const float kc = bflo(ci.x), qc = bfhi(ci.x);
                const float cn = __builtin_bit_cast(float, ci.y);
                unsigned wv = sKQg[base + 512 * r];
                float xj = bfu(sXg[base + 512 * r]);
                xj = colbad ? 0.f : xj;
                float e = __expf(fmaf(bflo(wv), qc, fmaf(kc, bfhi(wv), cn)));
                acc[r] = fmaf(e, xj, acc[r]);
            }
        }
        #pragma unroll
        for (int r = 0; r < 8; ++r)
            pre[off + r * 512 + tid] = f2bf(acc[r]);
    }
}

// ---------------------------------------------------------------------------
// Final BN apply + ReLU: bf16 in, f32 out (unchanged)
// ---------------------------------------------------------------------------
__global__ __launch_bounds__(256) void bn_apply_k(
    const ushort_t* __restrict__ yf,
    const float* __restrict__ scale, const float* __restrict__ shift,
    float* __restrict__ out)
{
    const int i = blockIdx.x * 256 + threadIdx.x;   // uint4 index (8 elems)
    const int ch = (i >> 9) & 255;
    const float sc = scale[ch], sh = shift[ch];

    uint4 v = ((const uint4*)yf)[i];
    unsigned w[4] = {v.x, v.y, v.z, v.w};
    float4 o0, o1;
    o0.x = fmaxf(fmaf(bflo(w[0]), sc, sh), 0.f);
    o0.y = fmaxf(fmaf(bfhi(w[0]), sc, sh), 0.f);
    o0.z = fmaxf(fmaf(bflo(w[1]), sc, sh), 0.f);
    o0.w = fmaxf(fmaf(bfhi(w[1]), sc, sh), 0.f);
    o1.x = fmaxf(fmaf(bflo(w[2]), sc, sh), 0.f);
    o1.y = fmaxf(fmaf(bfhi(w[2]), sc, sh), 0.f);
    o1.z = fmaxf(fmaf(bflo(w[3]), sc, sh), 0.f);
    o1.w = fmaxf(fmaf(bfhi(w[3]), sc, sh), 0.f);
    ((float4*)out)[2 * i]     = o0;
    ((float4*)out)[2 * i + 1] = o1;
}

// ---------------------------------------------------------------------------
extern "C" void kernel_launch(void* const* d_in, const int* in_sizes, int n_in,
                              void* d_out, int out_size, void* d_ws, size_t ws_size,
                              hipStream_t stream) {
    const float* x   = (const float*)d_in[0];
    const float* w1  = (const float*)d_in[1];
    const float* b1  = (const float*)d_in[2];
    const float* g1  = (const float*)d_in[3];
    const float* be1 = (const float*)d_in[4];
    const float* w2  = (const float*)d_in[5];
    const float* b2  = (const float*)d_in[6];
    const float* g2  = (const float*)d_in[7];
    const float* be2 = (const float*)d_in[8];
    const float* wf  = (const float*)d_in[9];
    const float* bf  = (const float*)d_in[10];
    const float* gf  = (const float*)d_in[11];
    const float* bef = (const float*)d_in[12];
    float* out = (float*)d_out;

    const size_t NEL = (size_t)NB * CCH * L;       // 4194304
    ushort_t* y1b = (ushort_t*)d_ws;               // conv1 out (bf16); later yf
    ushort_t* y2b = y1b + NEL;                     // conv2 out (bf16); later pre
    float* st = (float*)(y2b + NEL);               // stats: 6 x 256
    float* s1sc = st,        *s1sh = st + 256;
    float* s2sc = st + 512,  *s2sh = st + 768;
    float* sfsc = st + 1024, *sfsh = st + 1280;
    ushort_t* wb1 = (ushort_t*)(st + 1536);        // bf16 weights: 3 x 64K
    ushort_t* wb2 = wb1 + CCH * CCH;
    ushort_t* wbf = wb2 + CCH * CCH;

    wcvt_k<<<192, 256, 0, stream>>>(w1, w2, wf, wb1, wb2, wbf);
    dim3 gg(64, 2, 4);
    dual_gemm_k<<<gg, 256, 0, stream>>>(x, wb1, b1, wb2, b2, y1b, y2b);
    bn_stats2_k<<<512, 256, 0, stream>>>(y1b, g1, be1, s1sc, s1sh,
                                         y2b, g2, be2, s2sc, s2sh);
    attention_k<<<NB * CCH, 512, 0, stream>>>(x, y1b, y2b,
                                              s1sc, s1sh, s2sc, s2sh,
                                              /*pre=*/y2b);
    single_gemm_k<<<gg, 256, 0, stream>>>(/*pre=*/y2b, wbf, bf, /*yf=*/y1b);
    bn_stats_k<<<256, 256, 0, stream>>>(y1b, gf, bef, sfsc, sfsh);
    bn_apply_k<<<(int)(NEL / 2048), 256, 0, stream>>>(y1b, sfsc, sfsh, out);
}

// Round 14
// 157.708 us; speedup vs baseline: 1.4039x; 1.0176x over previous
//
#include <hip/hip_runtime.h>
#include <hip/hip_bf16.h>

#define L 4096
#define CCH 256
#define NB 4
#define KP 40   // padded LDS row length (32 k + 8 pad) in bf16 elems; 80 B rows
#define GOF 72  // guarded-image front offset (alignment-friendly, >= 65)
#define LOG2E 1.4426950408889634f

typedef __attribute__((ext_vector_type(8))) short short8;
typedef __attribute__((ext_vector_type(4))) float f32x4;
typedef unsigned short ushort_t;

__device__ __forceinline__ unsigned short f2bf(float f) {
    unsigned u = __builtin_bit_cast(unsigned, f);
    u += 0x7FFF + ((u >> 16) & 1);
    return (unsigned short)(u >> 16);
}
// packed RNE f32x2 -> bf16x2; kept in GEMM epilogues / staging
__device__ __forceinline__ unsigned pk_bf16(float a, float b) {
    __hip_bfloat162 h = __float22bfloat162_rn(make_float2(a, b));
    unsigned u;
    __builtin_memcpy(&u, &h, 4);
    return u;
}
__device__ __forceinline__ float bflo(unsigned w) {
    return __builtin_bit_cast(float, w << 16);
}
__device__ __forceinline__ float bfhi(unsigned w) {
    return __builtin_bit_cast(float, w & 0xFFFF0000u);
}
__device__ __forceinline__ float bfu(ushort_t h) {
    return __builtin_bit_cast(float, (unsigned)h << 16);
}

// ---------------------------------------------------------------------------
// One-time weight conversion: w1|w2|wf (each 256x256 f32) -> bf16
// ---------------------------------------------------------------------------
__global__ __launch_bounds__(256) void wcvt_k(
    const float* __restrict__ w1, const float* __restrict__ w2,
    const float* __restrict__ wf,
    ushort_t* __restrict__ wb1, ushort_t* __restrict__ wb2,
    ushort_t* __restrict__ wbf)
{
    const int mb = blockIdx.x >> 6;          // 0..2: which matrix
    const int i  = (blockIdx.x & 63) * 256 + threadIdx.x;   // float4 index
    const float* src = (mb == 0) ? w1 : (mb == 1) ? w2 : wf;
    ushort_t*    dst = (mb == 0) ? wb1 : (mb == 1) ? wb2 : wbf;
    float4 v = ((const float4*)src)[i];
    uint2 p;
    p.x = pk_bf16(v.x, v.y);
    p.y = pk_bf16(v.z, v.w);
    ((uint2*)dst)[i] = p;
}

// ---------------------------------------------------------------------------
// Dual conv1x1 via bf16 MFMA (unchanged R13)
// ---------------------------------------------------------------------------
__global__ __launch_bounds__(256, 2) void dual_gemm_k(
    const float* __restrict__ x,
    const ushort_t* __restrict__ wb1, const float* __restrict__ b1,
    const ushort_t* __restrict__ wb2, const float* __restrict__ b2,
    ushort_t* __restrict__ y1, ushort_t* __restrict__ y2)
{
    __shared__ short sA1[128 * KP];
    __shared__ short sA2[128 * KP];
    __shared__ short sB [64 * KP];

    const int tid = threadIdx.x;
    const int l0 = blockIdx.x * 64;
    const int o0 = blockIdx.y * 128;
    const int b  = blockIdx.z;

    const int wv = tid >> 6;
    const int lane = tid & 63;
    const int m = lane & 15;
    const int quad = lane >> 4;

    const float* xb = x + (size_t)b * CCH * L;

    const int sl = tid & 63, soct = tid >> 6;
    const int sr = tid & 127, sh = tid >> 7;

    f32x4 acc1[2][4], acc2[2][4];
    #pragma unroll
    for (int io = 0; io < 2; ++io)
        #pragma unroll
        for (int jl = 0; jl < 4; ++jl) {
            acc1[io][jl] = (f32x4){0.f,0.f,0.f,0.f};
            acc2[io][jl] = (f32x4){0.f,0.f,0.f,0.f};
        }

    for (int s = 0; s < 8; ++s) {
        const int k0 = s * 32;
        __syncthreads();
        {
            const float* xs = xb + (size_t)(k0 + soct * 8) * L + l0 + sl;
            float f[8];
            #pragma unroll
            for (int j = 0; j < 8; ++j) f[j] = xs[(size_t)j * L];
            uint4 v;
            v.x = pk_bf16(f[0], f[1]);
            v.y = pk_bf16(f[2], f[3]);
            v.z = pk_bf16(f[4], f[5]);
            v.w = pk_bf16(f[6], f[7]);
            *(uint4*)&sB[sl * KP + soct * 8] = v;
        }
        {
            const uint4* wp = (const uint4*)&wb1[(size_t)(o0 + sr) * CCH + k0 + sh * 16];
            uint4 p0 = wp[0], p1 = wp[1];
            *(uint4*)&sA1[sr * KP + sh * 16]     = p0;
            *(uint4*)&sA1[sr * KP + sh * 16 + 8] = p1;
            const uint4* wq = (const uint4*)&wb2[(size_t)(o0 + sr) * CCH + k0 + sh * 16];
            uint4 q0 = wq[0], q1 = wq[1];
            *(uint4*)&sA2[sr * KP + sh * 16]     = q0;
            *(uint4*)&sA2[sr * KP + sh * 16 + 8] = q1;
        }
        __syncthreads();
        short8 a1[2], a2[2], bf[4];
        #pragma unroll
        for (int io = 0; io < 2; ++io) {
            a1[io] = *(const short8*)&sA1[(wv * 32 + io * 16 + m) * KP + quad * 8];
            a2[io] = *(const short8*)&sA2[(wv * 32 + io * 16 + m) * KP + quad * 8];
        }
        #pragma unroll
        for (int jl = 0; jl < 4; ++jl)
            bf[jl] = *(const short8*)&sB[(jl * 16 + m) * KP + quad * 8];
        #pragma unroll
        for (int io = 0; io < 2; ++io)
            #pragma unroll
            for (int jl = 0; jl < 4; ++jl) {
                acc1[io][jl] = __builtin_amdgcn_mfma_f32_16x16x32_bf16(a1[io], bf[jl], acc1[io][jl], 0, 0, 0);
                acc2[io][jl] = __builtin_amdgcn_mfma_f32_16x16x32_bf16(a2[io], bf[jl], acc2[io][jl], 0, 0, 0);
            }
    }

    #pragma unroll
    for (int io = 0; io < 2; ++io)
        #pragma unroll
        for (int reg = 0; reg < 4; ++reg) {
            const int o = o0 + wv * 32 + io * 16 + quad * 4 + reg;
            const float bb1 = b1[o], bb2 = b2[o];
            const size_t ro = ((size_t)b * CCH + o) * L + l0 + m;
            unsigned u1a = pk_bf16(acc1[io][0][reg] + bb1, acc1[io][1][reg] + bb1);
            unsigned u1b = pk_bf16(acc1[io][2][reg] + bb1, acc1[io][3][reg] + bb1);
            unsigned u2a = pk_bf16(acc2[io][0][reg] + bb2, acc2[io][1][reg] + bb2);
            unsigned u2b = pk_bf16(acc2[io][2][reg] + bb2, acc2[io][3][reg] + bb2);
            y1[ro]      = (ushort_t)u1a;
            y1[ro + 16] = (ushort_t)(u1a >> 16);
            y1[ro + 32] = (ushort_t)u1b;
            y1[ro + 48] = (ushort_t)(u1b >> 16);
            y2[ro]      = (ushort_t)u2a;
            y2[ro + 16] = (ushort_t)(u2a >> 16);
            y2[ro + 32] = (ushort_t)u2b;
            y2[ro + 48] = (ushort_t)(u2b >> 16);
        }
}

// ---------------------------------------------------------------------------
// Single conv1x1 via bf16 MFMA (unchanged R13)
// ---------------------------------------------------------------------------
__global__ __launch_bounds__(256, 2) void single_gemm_k(
    const ushort_t* __restrict__ x,
    const ushort_t* __restrict__ wb, const float* __restrict__ bb,
    ushort_t* __restrict__ y)
{
    __shared__ short sA[128 * KP];
    __shared__ short sB[64 * KP];

    const int tid = threadIdx.x;
    const int l0 = blockIdx.x * 64;
    const int o0 = blockIdx.y * 128;
    const int b  = blockIdx.z;

    const int wv = tid >> 6;
    const int lane = tid & 63;
    const int m = lane & 15;
    const int quad = lane >> 4;

    const ushort_t* xb = x + (size_t)b * CCH * L;

    const int sl = tid & 63, soct = tid >> 6;
    const int sr = tid & 127, sh = tid >> 7;

    f32x4 acc[2][4];
    #pragma unroll
    for (int io = 0; io < 2; ++io)
        #pragma unroll
        for (int jl = 0; jl < 4; ++jl)
            acc[io][jl] = (f32x4){0.f,0.f,0.f,0.f};

    for (int s = 0; s < 8; ++s) {
        const int k0 = s * 32;
        __syncthreads();
        {
            const ushort_t* xs = xb + (size_t)(k0 + soct * 8) * L + l0 + sl;
            short8 v;
            #pragma unroll
            for (int j = 0; j < 8; ++j) v[j] = (short)xs[(size_t)j * L];
            *(short8*)&sB[sl * KP + soct * 8] = v;
        }
        {
            const uint4* wp = (const uint4*)&wb[(size_t)(o0 + sr) * CCH + k0 + sh * 16];
            uint4 p0 = wp[0], p1 = wp[1];
            *(uint4*)&sA[sr * KP + sh * 16]     = p0;
            *(uint4*)&sA[sr * KP + sh * 16 + 8] = p1;
        }
        __syncthreads();
        short8 a[2], bf[4];
        #pragma unroll
        for (int io = 0; io < 2; ++io)
            a[io] = *(const short8*)&sA[(wv * 32 + io * 16 + m) * KP + quad * 8];
        #pragma unroll
        for (int jl = 0; jl < 4; ++jl)
            bf[jl] = *(const short8*)&sB[(jl * 16 + m) * KP + quad * 8];
        #pragma unroll
        for (int io = 0; io < 2; ++io)
            #pragma unroll
            for (int jl = 0; jl < 4; ++jl)
                acc[io][jl] = __builtin_amdgcn_mfma_f32_16x16x32_bf16(a[io], bf[jl], acc[io][jl], 0, 0, 0);
    }

    #pragma unroll
    for (int io = 0; io < 2; ++io)
        #pragma unroll
        for (int reg = 0; reg < 4; ++reg) {
            const int o = o0 + wv * 32 + io * 16 + quad * 4 + reg;
            const float b0 = bb[o];
            const size_t ro = ((size_t)b * CCH + o) * L + l0 + m;
            unsigned ua = pk_bf16(acc[io][0][reg] + b0, acc[io][1][reg] + b0);
            unsigned ub = pk_bf16(acc[io][2][reg] + b0, acc[io][3][reg] + b0);
            y[ro]      = (ushort_t)ua;
            y[ro + 16] = (ushort_t)(ua >> 16);
            y[ro + 32] = (ushort_t)ub;
            y[ro + 48] = (ushort_t)(ub >> 16);
        }
}

// ---------------------------------------------------------------------------
// BatchNorm stats over bf16 tensor -> finalized scale/shift.
// kscale: extra factor folded into scale/shift (log2e for the K channel).
// ---------------------------------------------------------------------------
__device__ __forceinline__ void bn_stats_body(
    const ushort_t* y, const float* gamma, const float* beta,
    float* scale, float* shift, int c, int tid, float kscale)
{
    float s = 0.f, s2 = 0.f;
    for (int b = 0; b < NB; ++b) {
        const uint4* p = (const uint4*)(y + ((size_t)b * CCH + c) * L);
        #pragma unroll
        for (int r = 0; r < 2; ++r) {
            uint4 v = p[r * 256 + tid];
            unsigned w[4] = {v.x, v.y, v.z, v.w};
            #pragma unroll
            for (int u = 0; u < 4; ++u) {
                float a = bflo(w[u]), bb = bfhi(w[u]);
                s  += a + bb;
                s2 += a * a + bb * bb;
            }
        }
    }
    #pragma unroll
    for (int off = 32; off > 0; off >>= 1) {
        s  += __shfl_down(s, off);
        s2 += __shfl_down(s2, off);
    }
    __shared__ float red[2][4];
    if ((tid & 63) == 0) { red[0][tid >> 6] = s; red[1][tid >> 6] = s2; }
    __syncthreads();
    if (tid == 0) {
        float S  = red[0][0] + red[0][1] + red[0][2] + red[0][3];
        float S2 = red[1][0] + red[1][1] + red[1][2] + red[1][3];
        const float invN = 1.f / (NB * (float)L);
        float mean = S * invN;
        float var  = S2 * invN - mean * mean;
        float rstd = rsqrtf(var + 1e-5f);
        float g = gamma[c];
        scale[c] = kscale * g * rstd;
        shift[c] = kscale * (beta[c] - mean * g * rstd);
    }
}

// two tensors in one launch: blockIdx.x in [0,512). K channel gets log2e fold.
__global__ __launch_bounds__(256) void bn_stats2_k(
    const ushort_t* __restrict__ y1, const float* __restrict__ g1, const float* __restrict__ be1,
    float* __restrict__ sc1, float* __restrict__ sh1,
    const ushort_t* __restrict__ y2, const float* __restrict__ g2, const float* __restrict__ be2,
    float* __restrict__ sc2, float* __restrict__ sh2)
{
    const int c = blockIdx.x & 255;
    if (blockIdx.x < 256) bn_stats_body(y1, g1, be1, sc1, sh1, c, threadIdx.x, LOG2E);
    else                  bn_stats_body(y2, g2, be2, sc2, sh2, c, threadIdx.x, 1.0f);
}

// ---------------------------------------------------------------------------
// Attention v3 (R13 structure) with exp2 path: K pre-scaled by log2e (folded
// into sc1/sh1; ReLU commutes with positive scale), exps are bare v_exp_f32,
// denominator folded as -log2(S).
// ---------------------------------------------------------------------------
__global__ __launch_bounds__(512, 4) void attention_k(
    const float* __restrict__ x,
    const ushort_t* __restrict__ y1,
    const ushort_t* __restrict__ y2,
    const float* __restrict__ s1sc, const float* __restrict__ s1sh,
    const float* __restrict__ s2sc, const float* __restrict__ s2sh,
    ushort_t* __restrict__ pre)
{
    __shared__ unsigned sKQg[4240];   // [GOF+s] = packed bf16 (k', q); guards zero
    __shared__ ushort_t sXg [4240];   // [GOF+s] = bf16 x; guards zero
    __shared__ uint2    sCI [L];      // {packed (kc',qc), bits(-log2 S)} per window

    const int bc = blockIdx.x;
    const int tid = threadIdx.x;
    const int ch = bc & 255;
    const size_t off = (size_t)bc * L;

    const float sc1 = s1sc[ch], sh1 = s1sh[ch];   // pre-scaled by log2e
    const float sc2 = s2sc[ch], sh2 = s2sh[ch];

    // ---- stage + guards ----------------------------------------------
    if (tid < GOF)  { sKQg[tid] = 0; sXg[tid] = 0; }
    if (tid < 72)   { sKQg[GOF + 4096 + tid] = 0; sXg[GOF + 4096 + tid] = 0; }
    {
        uint4 ak = ((const uint4*)(y1 + off))[tid];
        uint4 aq = ((const uint4*)(y2 + off))[tid];
        float4 xa = ((const float4*)(x + off))[2 * tid];
        float4 xb = ((const float4*)(x + off))[2 * tid + 1];
        unsigned wk[4] = {ak.x, ak.y, ak.z, ak.w};
        unsigned wq[4] = {aq.x, aq.y, aq.z, aq.w};
        unsigned kq[8];
        #pragma unroll
        for (int u = 0; u < 4; ++u) {
            float klo = fmaxf(fmaf(bflo(wk[u]), sc1, sh1), 0.f);
            float khi = fmaxf(fmaf(bfhi(wk[u]), sc1, sh1), 0.f);
            float qlo = fmaxf(fmaf(bflo(wq[u]), sc2, sh2), 0.f);
            float qhi = fmaxf(fmaf(bfhi(wq[u]), sc2, sh2), 0.f);
            kq[2*u]   = (unsigned)f2bf(klo) | ((unsigned)f2bf(qlo) << 16);
            kq[2*u+1] = (unsigned)f2bf(khi) | ((unsigned)f2bf(qhi) << 16);
        }
        *(uint4*)&sKQg[GOF + 8 * tid]     = make_uint4(kq[0], kq[1], kq[2], kq[3]);
        *(uint4*)&sKQg[GOF + 8 * tid + 4] = make_uint4(kq[4], kq[5], kq[6], kq[7]);
        float xv[8] = {xa.x, xa.y, xa.z, xa.w, xb.x, xb.y, xb.z, xb.w};
        unsigned xp[4];
        #pragma unroll
        for (int u = 0; u < 4; ++u)
            xp[u] = (unsigned)f2bf(xv[2*u]) | ((unsigned)f2bf(xv[2*u+1]) << 16);
        *(uint4*)&sXg[GOF + 8 * tid] = make_uint4(xp[0], xp[1], xp[2], xp[3]);
    }
    __syncthreads();

    // ---- Phase 1: per-window center + -log2(denominator) --------------
    {
        const int fbase = 9 * tid;
        #pragma unroll
        for (int r = 0; r < 8; ++r) {
            const int f  = fbase + 4608 * r;
            const int t  = f >> 12;
            const int fl = f & 4095;
            unsigned wv[9];
            if (fl < 4088) {                       // fast path: single tap t
                const int di = (t * 86) >> 8;
                const int dj = t - 3 * di;
                const int cbad = (dj == 0) ? 0 : ((dj == 2) ? 63 : 99);
                const int base = fl + (di << 6) + dj - 65 + GOF;
                #pragma unroll
                for (int j = 0; j < 9; ++j) wv[j] = sKQg[base + j];
                #pragma unroll
                for (int j = 0; j < 9; ++j) {
                    int c = (fl + j) & 63;
                    wv[j] = (c == cbad) ? 0u : wv[j];
                }
            } else {                               // straddle: generic decode
                #pragma unroll
                for (int j = 0; j < 9; ++j) {
                    int fj = f + j;
                    int tj = fj >> 12, lj = fj & 4095;
                    int dij = (tj * 86) >> 8, djj = tj - 3 * dij;
                    int idx = lj + (dij << 6) + djj - 65 + GOF;
                    unsigned wr = sKQg[idx];
                    int c = lj & 63;
                    int cb = (djj == 0) ? 0 : ((djj == 2) ? 63 : 99);
                    wv[j] = (c == cb) ? 0u : wr;
                }
            }
            const unsigned cw = wv[4];
            const float kc = bflo(cw), qc = bfhi(cw);
            float e0 = __builtin_amdgcn_exp2f(bflo(wv[0]) * qc + kc * bfhi(wv[0]));
            float e1 = __builtin_amdgcn_exp2f(bflo(wv[1]) * qc + kc * bfhi(wv[1]));
            float e2 = __builtin_amdgcn_exp2f(bflo(wv[2]) * qc + kc * bfhi(wv[2]));
            float e3 = __builtin_amdgcn_exp2f(bflo(wv[3]) * qc + kc * bfhi(wv[3]));
            float e4 = __builtin_amdgcn_exp2f(bflo(wv[4]) * qc + kc * bfhi(wv[4]));
            float e5 = __builtin_amdgcn_exp2f(bflo(wv[5]) * qc + kc * bfhi(wv[5]));
            float e6 = __builtin_amdgcn_exp2f(bflo(wv[6]) * qc + kc * bfhi(wv[6]));
            float e7 = __builtin_amdgcn_exp2f(bflo(wv[7]) * qc + kc * bfhi(wv[7]));
            float e8 = __builtin_amdgcn_exp2f(bflo(wv[8]) * qc + kc * bfhi(wv[8]));
            float s = (((e0 + e1) + (e2 + e3)) + ((e4 + e5) + (e6 + e7))) + e8;
            uint2 ci;
            ci.x = cw;
            ci.y = __builtin_bit_cast(unsigned, -__builtin_amdgcn_logf(s));
            sCI[r * 512 + tid] = ci;
        }
    }
    __syncthreads();

    // ---- Phase 2: per-output accumulate; outputs l = r*512 + tid ------
    {
        const int c0 = tid & 63;
        float acc[8];
        #pragma unroll
        for (int r = 0; r < 8; ++r) acc[r] = 0.f;

        #pragma unroll
        for (int t = 0; t < 9; ++t) {
            const int di = t / 3, dj = t % 3;
            const int base = tid + (di << 6) + dj - 65 + GOF;
            const bool colbad = (dj == 0) ? (c0 == 0) : ((dj == 2) ? (c0 == 63) : false);
            const int ft = (t << 12) + tid;
            #pragma unroll
            for (int r = 0; r < 8; ++r) {
                const int f = ft + 512 * r;
                const unsigned lp = (unsigned)f / 9u;
                uint2 ci = sCI[lp];
                const float kc = bflo(ci.x), qc = bfhi(ci.x);
                const float cn = __builtin_bit_cast(float, ci.y);
                unsigned wv = sKQg[base + 512 * r];
                float xj = bfu(sXg[base + 512 * r]);
                xj = colbad ? 0.f : xj;
                float e = __builtin_amdgcn_exp2f(fmaf(bflo(wv), qc, fmaf(kc, bfhi(wv), cn)));
                acc[r] = fmaf(e, xj, acc[r]);
            }
        }
        #pragma unroll
        for (int r = 0; r < 8; ++r)
            pre[off + r * 512 + tid] = f2bf(acc[r]);
    }
}

// ---------------------------------------------------------------------------
// Fused final BN: per-channel stats + apply + ReLU in one kernel.
// Block c: stage channel's 4x4096 bf16 (32 KB LDS), reduce, finalize, apply.
// ---------------------------------------------------------------------------
__global__ __launch_bounds__(256) void bn_fused_k(
    const ushort_t* __restrict__ yf,
    const float* __restrict__ gf, const float* __restrict__ bef,
    float* __restrict__ out)
{
    __shared__ uint4 sY[2048];       // 4 batches x 512 uint4 = 32 KB
    __shared__ float red[2][4];
    __shared__ float fsc, fsh;

    const int c = blockIdx.x, tid = threadIdx.x;
    float s = 0.f, s2 = 0.f;
    #pragma unroll
    for (int b = 0; b < NB; ++b) {
        const uint4* p = (const uint4*)(yf + ((size_t)b * CCH + c) * L);
        #pragma unroll
        for (int r = 0; r < 2; ++r) {
            uint4 v = p[r * 256 + tid];
            sY[b * 512 + r * 256 + tid] = v;
            unsigned w[4] = {v.x, v.y, v.z, v.w};
            #pragma unroll
            for (int u = 0; u < 4; ++u) {
                float a = bflo(w[u]), bb = bfhi(w[u]);
                s  += a + bb;
                s2 += a * a + bb * bb;
            }
        }
    }
    #pragma unroll
    for (int off = 32; off > 0; off >>= 1) {
        s  += __shfl_down(s, off);
        s2 += __shfl_down(s2, off);
    }
    if ((tid & 63) == 0) { red[0][tid >> 6] = s; red[1][tid >> 6] = s2; }
    __syncthreads();
    if (tid == 0) {
        float S  = red[0][0] + red[0][1] + red[0][2] + red[0][3];
        float S2 = red[1][0] + red[1][1] + red[1][2] + red[1][3];
        const float invN = 1.f / (NB * (float)L);
        float mean = S * invN;
        float var  = S2 * invN - mean * mean;
        float rstd = rsqrtf(var + 1e-5f);
        float g = gf[c];
        fsc = g * rstd;
        fsh = bef[c] - mean * g * rstd;
    }
    __syncthreads();
    const float sc = fsc, sh = fsh;

    #pragma unroll
    for (int b = 0; b < NB; ++b) {
        float4* o = (float4*)(out + ((size_t)b * CCH + c) * L);
        #pragma unroll
        for (int r = 0; r < 2; ++r) {
            uint4 v = sY[b * 512 + r * 256 + tid];
            unsigned w[4] = {v.x, v.y, v.z, v.w};
            float4 o0, o1;
            o0.x = fmaxf(fmaf(bflo(w[0]), sc, sh), 0.f);
            o0.y = fmaxf(fmaf(bfhi(w[0]), sc, sh), 0.f);
            o0.z = fmaxf(fmaf(bflo(w[1]), sc, sh), 0.f);
            o0.w = fmaxf(fmaf(bfhi(w[1]), sc, sh), 0.f);
            o1.x = fmaxf(fmaf(bflo(w[2]), sc, sh), 0.f);
            o1.y = fmaxf(fmaf(bfhi(w[2]), sc, sh), 0.f);
            o1.z = fmaxf(fmaf(bflo(w[3]), sc, sh), 0.f);
            o1.w = fmaxf(fmaf(bfhi(w[3]), sc, sh), 0.f);
            int i = r * 256 + tid;
            o[2 * i]     = o0;
            o[2 * i + 1] = o1;
        }
    }
}

// ---------------------------------------------------------------------------
extern "C" void kernel_launch(void* const* d_in, const int* in_sizes, int n_in,
                              void* d_out, int out_size, void* d_ws, size_t ws_size,
                              hipStream_t stream) {
    const float* x   = (const float*)d_in[0];
    const float* w1  = (const float*)d_in[1];
    const float* b1  = (const float*)d_in[2];
    const float* g1  = (const float*)d_in[3];
    const float* be1 = (const float*)d_in[4];
    const float* w2  = (const float*)d_in[5];
    const float* b2  = (const float*)d_in[6];
    const float* g2  = (const float*)d_in[7];
    const float* be2 = (const float*)d_in[8];
    const float* wf  = (const float*)d_in[9];
    const float* bf  = (const float*)d_in[10];
    const float* gf  = (const float*)d_in[11];
    const float* bef = (const float*)d_in[12];
    float* out = (float*)d_out;

    const size_t NEL = (size_t)NB * CCH * L;       // 4194304
    ushort_t* y1b = (ushort_t*)d_ws;               // conv1 out (bf16); later yf
    ushort_t* y2b = y1b + NEL;                     // conv2 out (bf16); later pre
    float* st = (float*)(y2b + NEL);               // stats: 4 x 256
    float* s1sc = st,        *s1sh = st + 256;
    float* s2sc = st + 512,  *s2sh = st + 768;
    ushort_t* wb1 = (ushort_t*)(st + 1536);        // bf16 weights: 3 x 64K
    ushort_t* wb2 = wb1 + CCH * CCH;
    ushort_t* wbf = wb2 + CCH * CCH;

    wcvt_k<<<192, 256, 0, stream>>>(w1, w2, wf, wb1, wb2, wbf);
    dim3 gg(64, 2, 4);
    dual_gemm_k<<<gg, 256, 0, stream>>>(x, wb1, b1, wb2, b2, y1b, y2b);
    bn_stats2_k<<<512, 256, 0, stream>>>(y1b, g1, be1, s1sc, s1sh,
                                         y2b, g2, be2, s2sc, s2sh);
    attention_k<<<NB * CCH, 512, 0, stream>>>(x, y1b, y2b,
                                              s1sc, s1sh, s2sc, s2sh,
                                              /*pre=*/y2b);
    single_gemm_k<<<gg, 256, 0, stream>>>(/*pre=*/y2b, wbf, bf, /*yf=*/y1b);
    bn_fused_k<<<256, 256, 0, stream>>>(y1b, gf, bef, out);
}